// Round 1
// baseline (1477.600 us; speedup 1.0000x reference)
//
#include <hip/hip_runtime.h>
#include <cstdint>
#include <cstddef>

// ---------- types ----------
typedef float  floatx4 __attribute__((ext_vector_type(4)));
typedef short  short8  __attribute__((ext_vector_type(8)));
typedef unsigned short usx4 __attribute__((ext_vector_type(4)));

// fp32 -> bf16, round-to-nearest-even
__device__ __forceinline__ unsigned short f2b(float f) {
  unsigned u = __float_as_uint(f);
  unsigned r = u + 0x7fffu + ((u >> 16) & 1u);
  return (unsigned short)(r >> 16);
}

__device__ __forceinline__ float gelu_f(float x) {
  const float c = 0.7978845608028654f; // sqrt(2/pi)
  float t = tanhf(c * (x + 0.044715f * x * x * x));
  return 0.5f * x * (1.0f + t);
}

// ---------- LayerNorm: one block per row of 1024 ----------
__global__ __launch_bounds__(256) void ln_kernel(
    const float* __restrict__ in, const float* __restrict__ w,
    const float* __restrict__ b, float* __restrict__ out)
{
  const int row = blockIdx.x;
  const int t = threadIdx.x;
  const float* p = in + (size_t)row * 1024 + t * 4;
  floatx4 v = *(const floatx4*)p;
  float s  = v.x + v.y + v.z + v.w;
  float ss = v.x*v.x + v.y*v.y + v.z*v.z + v.w*v.w;
  #pragma unroll
  for (int m = 1; m < 64; m <<= 1) {
    s  += __shfl_xor(s,  m);
    ss += __shfl_xor(ss, m);
  }
  __shared__ float red[8];
  if ((t & 63) == 0) { red[(t >> 6)*2] = s; red[(t >> 6)*2 + 1] = ss; }
  __syncthreads();
  s  = red[0] + red[2] + red[4] + red[6];
  ss = red[1] + red[3] + red[5] + red[7];
  const float mean = s * (1.0f / 1024.0f);
  const float var  = ss * (1.0f / 1024.0f) - mean * mean;
  const float rstd = rsqrtf(var + 1e-6f);
  floatx4 wv = *(const floatx4*)(w + t * 4);
  floatx4 bv = *(const floatx4*)(b + t * 4);
  floatx4 o;
  o.x = wv.x * ((v.x - mean) * rstd) + bv.x;
  o.y = wv.y * ((v.y - mean) * rstd) + bv.y;
  o.z = wv.z * ((v.z - mean) * rstd) + bv.z;
  o.w = wv.w * ((v.w - mean) * rstd) + bv.w;
  *(floatx4*)(out + (size_t)row * 1024 + t * 4) = o;
}

// ---------- GEMM: C[M,N] = A[M,K] @ B[K,N] + bias (+gelu) (+residual) ----------
// 64x64 tile, BK=32, 256 threads (4 waves), mfma_f32_16x16x32_bf16.
// flags: 1 = gelu, 2 = residual add (Res same shape as C)
__global__ __launch_bounds__(256) void gemm_kernel(
    const float* __restrict__ A, const float* __restrict__ B,
    const float* __restrict__ bias, const float* __restrict__ Res,
    float* __restrict__ C, int M, int N, int K, int flags)
{
  __shared__ unsigned short As[64][36];  // A tile, row-major, k-contiguous (pad 32->36)
  __shared__ unsigned short Bs[64][36];  // B^T tile: Bs[n][k]

  const int tid  = threadIdx.x;
  const int wave = tid >> 6;
  const int lane = tid & 63;
  const int quad = lane >> 4;
  const int l16  = lane & 15;
  const int bm0 = blockIdx.y * 64;
  const int bn0 = blockIdx.x * 64;

  // staging coords
  const int arow = tid >> 2;          // 0..63
  const int ac   = (tid & 3) * 8;     // 0,8,16,24
  const int bn   = tid & 63;          // 0..63
  const int bkg  = tid >> 6;          // 0..3 (k-group of 8)

  floatx4 acc[4] = {};

  const float* aBase = A + (size_t)(bm0 + arow) * K + ac;
  const float* bBase = B + (size_t)(bkg * 8) * N + bn0 + bn;

  for (int k0 = 0; k0 < K; k0 += 32) {
    // ---- stage A tile (coalesced float4 x2, convert to bf16) ----
    floatx4 a0 = *(const floatx4*)(aBase + k0);
    floatx4 a1 = *(const floatx4*)(aBase + k0 + 4);
    usx4 ua0 = { f2b(a0.x), f2b(a0.y), f2b(a0.z), f2b(a0.w) };
    usx4 ua1 = { f2b(a1.x), f2b(a1.y), f2b(a1.z), f2b(a1.w) };
    *(usx4*)&As[arow][ac]     = ua0;
    *(usx4*)&As[arow][ac + 4] = ua1;
    // ---- stage B^T tile (8 coalesced dword loads down k, vector LDS write) ----
    const float* bp = bBase + (size_t)k0 * N;
    float bv0 = bp[0];
    float bv1 = bp[(size_t)1 * N];
    float bv2 = bp[(size_t)2 * N];
    float bv3 = bp[(size_t)3 * N];
    float bv4 = bp[(size_t)4 * N];
    float bv5 = bp[(size_t)5 * N];
    float bv6 = bp[(size_t)6 * N];
    float bv7 = bp[(size_t)7 * N];
    usx4 ub0 = { f2b(bv0), f2b(bv1), f2b(bv2), f2b(bv3) };
    usx4 ub1 = { f2b(bv4), f2b(bv5), f2b(bv6), f2b(bv7) };
    *(usx4*)&Bs[bn][bkg*8]     = ub0;
    *(usx4*)&Bs[bn][bkg*8 + 4] = ub1;
    __syncthreads();

    // ---- MFMA: wave computes rows [wave*16, wave*16+16) x all 64 cols ----
    union { usx4 u4[2]; short8 s8; } af, bf;
    af.u4[0] = *(usx4*)&As[wave*16 + l16][quad*8];
    af.u4[1] = *(usx4*)&As[wave*16 + l16][quad*8 + 4];
    #pragma unroll
    for (int tno = 0; tno < 4; ++tno) {
      bf.u4[0] = *(usx4*)&Bs[tno*16 + l16][quad*8];
      bf.u4[1] = *(usx4*)&Bs[tno*16 + l16][quad*8 + 4];
      acc[tno] = __builtin_amdgcn_mfma_f32_16x16x32_bf16(af.s8, bf.s8, acc[tno], 0, 0, 0);
    }
    __syncthreads();
  }

  // ---- epilogue: C/D layout col=lane&15, row=quad*4+reg ----
  #pragma unroll
  for (int tno = 0; tno < 4; ++tno) {
    const int col = bn0 + tno*16 + l16;
    const float bvs = bias[col];
    #pragma unroll
    for (int r = 0; r < 4; ++r) {
      const int row = bm0 + wave*16 + quad*4 + r;
      float v = acc[tno][r] + bvs;
      if (flags & 1) v = gelu_f(v);
      if (flags & 2) v += Res[(size_t)row * N + col];
      C[(size_t)row * N + col] = v;
    }
  }
}

// ---------- Flash attention (causal), fp32 ----------
// grid: (S/16, H, B); block 256 = 4 waves; wave handles 4 q-rows.
// qkv: [B,S,3*1024] fp32, q at +h*64, k at +1024+h*64, v at +2048+h*64
// out: [B,S,1024] fp32
__global__ __launch_bounds__(256) void attn_kernel(
    const float* __restrict__ qkv, float* __restrict__ out)
{
  __shared__ floatx4 Q4[16][17];   // 16 q-rows x 64 dh (pad to 68 floats)
  __shared__ floatx4 K4[64][17];
  __shared__ floatx4 V4[64][17];
  __shared__ float   P[16][68];

  const int t    = threadIdx.x;
  const int q0   = blockIdx.x * 16;
  const int h    = blockIdx.y;
  const int b    = blockIdx.z;
  const int wave = t >> 6;
  const int lane = t & 63;

  const size_t base = (size_t)b * 2048 * 3072;
  const int qoff = h * 64;
  const int koff = 1024 + h * 64;
  const int voff = 2048 + h * 64;

  // stage Q once: 16 rows x 16 float4
  {
    const int r  = t >> 4;
    const int c4 = t & 15;
    Q4[r][c4] = *(const floatx4*)(qkv + base + (size_t)(q0 + r) * 3072 + qoff + c4 * 4);
  }

  float m[4], l[4], o[4];
  #pragma unroll
  for (int rr = 0; rr < 4; ++rr) { m[rr] = -1e30f; l[rr] = 0.f; o[rr] = 0.f; }

  const int ntiles = q0 / 64 + 1;
  const int jrow = t >> 2;         // 0..63
  const int jc   = (t & 3) * 4;    // float4 col base

  for (int tile = 0; tile < ntiles; ++tile) {
    const int k0 = tile * 64;
    __syncthreads();
    #pragma unroll
    for (int i = 0; i < 4; ++i) {
      const size_t rowb = base + (size_t)(k0 + jrow) * 3072;
      K4[jrow][jc + i] = *(const floatx4*)(qkv + rowb + koff + (jc + i) * 4);
      V4[jrow][jc + i] = *(const floatx4*)(qkv + rowb + voff + (jc + i) * 4);
    }
    __syncthreads();

    // scores: lane j = this lane's key
    float s[4] = {0.f, 0.f, 0.f, 0.f};
    #pragma unroll 4
    for (int d4 = 0; d4 < 16; ++d4) {
      floatx4 kv = K4[lane][d4];
      #pragma unroll
      for (int rr = 0; rr < 4; ++rr) {
        floatx4 qv = Q4[wave*4 + rr][d4];
        s[rr] += qv.x*kv.x + qv.y*kv.y + qv.z*kv.z + qv.w*kv.w;
      }
    }
    const int key = k0 + lane;
    float alpha[4];
    #pragma unroll
    for (int rr = 0; rr < 4; ++rr) {
      const int qrow = q0 + wave*4 + rr;
      float sv = s[rr] * 0.125f;             // 1/sqrt(64)
      if (key > qrow) sv = -1e30f;           // causal mask
      float mx = sv;
      #pragma unroll
      for (int msk = 1; msk < 64; msk <<= 1) mx = fmaxf(mx, __shfl_xor(mx, msk));
      const float nm = fmaxf(m[rr], mx);
      const float p  = __expf(sv - nm);
      float rs = p;
      #pragma unroll
      for (int msk = 1; msk < 64; msk <<= 1) rs += __shfl_xor(rs, msk);
      alpha[rr] = __expf(m[rr] - nm);
      m[rr] = nm;
      l[rr] = l[rr] * alpha[rr] + rs;
      P[wave*4 + rr][lane] = p;
    }
    __syncthreads();

    // PV: lane d = this lane's dh element
    const float* Vf = (const float*)V4;
    #pragma unroll
    for (int rr = 0; rr < 4; ++rr) o[rr] *= alpha[rr];
    for (int j = 0; j < 64; ++j) {
      const float vj = Vf[j * 68 + lane];
      #pragma unroll
      for (int rr = 0; rr < 4; ++rr) o[rr] += P[wave*4 + rr][j] * vj;
    }
  }

  #pragma unroll
  for (int rr = 0; rr < 4; ++rr) {
    const int qrow = q0 + wave*4 + rr;
    out[((size_t)b * 2048 + qrow) * 1024 + h * 64 + lane] = o[rr] / l[rr];
  }
}

// ---------- launch ----------
extern "C" void kernel_launch(void* const* d_in, const int* in_sizes, int n_in,
                              void* d_out, int out_size, void* d_ws, size_t ws_size,
                              hipStream_t stream) {
  const float* hidden    = (const float*)d_in[0];
  const float* w_attn    = (const float*)d_in[1];
  const float* b_attn    = (const float*)d_in[2];
  const float* w_proj    = (const float*)d_in[3];
  const float* b_proj    = (const float*)d_in[4];
  const float* w_fc      = (const float*)d_in[5];
  const float* b_fc      = (const float*)d_in[6];
  const float* w_fc_proj = (const float*)d_in[7];
  const float* b_fc_proj = (const float*)d_in[8];
  const float* ln1_w     = (const float*)d_in[9];
  const float* ln1_b     = (const float*)d_in[10];
  const float* ln2_w     = (const float*)d_in[11];
  const float* ln2_b     = (const float*)d_in[12];

  float* ws   = (float*)d_ws;
  float* x    = ws;              // 4096*1024
  float* qkv  = ws + 4194304;    // 4096*3072
  float* attn = ws + 16777216;   // 4096*1024
  float* h    = ws + 20971520;   // 4096*1024
  float* fc   = ws + 4194304;    // 4096*4096 (reuses qkv+attn, both dead)
  float* y    = ws;              // reuses x (dead after qkv GEMM)
  float* outp = (float*)d_out;

  // 1) x = LN1(hidden)
  ln_kernel<<<4096, 256, 0, stream>>>(hidden, ln1_w, ln1_b, x);
  // 2) qkv = x @ w_attn + b_attn   [4096,3072]
  gemm_kernel<<<dim3(3072/64, 4096/64), 256, 0, stream>>>(
      x, w_attn, b_attn, nullptr, qkv, 4096, 3072, 1024, 0);
  // 3) attn = softmax(q k^T / 8, causal) v   [4096,1024]
  attn_kernel<<<dim3(2048/16, 16, 2), 256, 0, stream>>>(qkv, attn);
  // 4) h = hidden + attn @ w_proj + b_proj
  gemm_kernel<<<dim3(1024/64, 4096/64), 256, 0, stream>>>(
      attn, w_proj, b_proj, hidden, h, 4096, 1024, 1024, 2);
  // 5) y = LN2(h)
  ln_kernel<<<4096, 256, 0, stream>>>(h, ln2_w, ln2_b, y);
  // 6) fc = gelu(y @ w_fc + b_fc)   [4096,4096]
  gemm_kernel<<<dim3(4096/64, 4096/64), 256, 0, stream>>>(
      y, w_fc, b_fc, nullptr, fc, 4096, 4096, 1024, 1);
  // 7) out = h + fc @ w_fc_proj + b_fc_proj
  gemm_kernel<<<dim3(1024/64, 4096/64), 256, 0, stream>>>(
      fc, w_fc_proj, b_fc_proj, h, outp, 4096, 1024, 4096, 2);
}

// Round 2
// 680.509 us; speedup vs baseline: 2.1713x; 2.1713x over previous
//
#include <hip/hip_runtime.h>
#include <cstdint>
#include <cstddef>

// ---------- types ----------
typedef float  floatx4 __attribute__((ext_vector_type(4)));
typedef short  short8  __attribute__((ext_vector_type(8)));
typedef unsigned short usx4 __attribute__((ext_vector_type(4)));

// fp32 -> bf16, round-to-nearest-even
__device__ __forceinline__ unsigned short f2b(float f) {
  unsigned u = __float_as_uint(f);
  unsigned r = u + 0x7fffu + ((u >> 16) & 1u);
  return (unsigned short)(r >> 16);
}
__device__ __forceinline__ float b2f(unsigned short s) {
  return __uint_as_float(((unsigned)s) << 16);
}

__device__ __forceinline__ float gelu_f(float x) {
  const float c = 0.7978845608028654f; // sqrt(2/pi)
  float t = tanhf(c * (x + 0.044715f * x * x * x));
  return 0.5f * x * (1.0f + t);
}

// ---------- LayerNorm: one block per row of 1024 ----------
__global__ __launch_bounds__(256) void ln_kernel(
    const float* __restrict__ in, const float* __restrict__ w,
    const float* __restrict__ b, float* __restrict__ out)
{
  const int row = blockIdx.x;
  const int t = threadIdx.x;
  const float* p = in + (size_t)row * 1024 + t * 4;
  floatx4 v = *(const floatx4*)p;
  float s  = v.x + v.y + v.z + v.w;
  float ss = v.x*v.x + v.y*v.y + v.z*v.z + v.w*v.w;
  #pragma unroll
  for (int m = 1; m < 64; m <<= 1) {
    s  += __shfl_xor(s,  m);
    ss += __shfl_xor(ss, m);
  }
  __shared__ float red[8];
  if ((t & 63) == 0) { red[(t >> 6)*2] = s; red[(t >> 6)*2 + 1] = ss; }
  __syncthreads();
  s  = red[0] + red[2] + red[4] + red[6];
  ss = red[1] + red[3] + red[5] + red[7];
  const float mean = s * (1.0f / 1024.0f);
  const float var  = ss * (1.0f / 1024.0f) - mean * mean;
  const float rstd = rsqrtf(var + 1e-6f);
  floatx4 wv = *(const floatx4*)(w + t * 4);
  floatx4 bv = *(const floatx4*)(b + t * 4);
  floatx4 o;
  o.x = wv.x * ((v.x - mean) * rstd) + bv.x;
  o.y = wv.y * ((v.y - mean) * rstd) + bv.y;
  o.z = wv.z * ((v.z - mean) * rstd) + bv.z;
  o.w = wv.w * ((v.w - mean) * rstd) + bv.w;
  *(floatx4*)(out + (size_t)row * 1024 + t * 4) = o;
}

// ---------- GEMM: C[M,N] = A[M,K] @ B[K,N] + bias (+gelu) (+residual) ----------
// 64x64 tile, BK=32, 256 threads (4 waves), mfma_f32_16x16x32_bf16.
// flags: 1 = gelu, 2 = residual add (Res same shape as C)
__global__ __launch_bounds__(256) void gemm_kernel(
    const float* __restrict__ A, const float* __restrict__ B,
    const float* __restrict__ bias, const float* __restrict__ Res,
    float* __restrict__ C, int M, int N, int K, int flags)
{
  __shared__ unsigned short As[64][36];  // A tile, row-major, k-contiguous (pad 32->36)
  __shared__ unsigned short Bs[64][36];  // B^T tile: Bs[n][k]

  const int tid  = threadIdx.x;
  const int wave = tid >> 6;
  const int lane = tid & 63;
  const int quad = lane >> 4;
  const int l16  = lane & 15;
  const int bm0 = blockIdx.y * 64;
  const int bn0 = blockIdx.x * 64;

  // staging coords
  const int arow = tid >> 2;          // 0..63
  const int ac   = (tid & 3) * 8;     // 0,8,16,24
  const int bn   = tid & 63;          // 0..63
  const int bkg  = tid >> 6;          // 0..3 (k-group of 8)

  floatx4 acc[4] = {};

  const float* aBase = A + (size_t)(bm0 + arow) * K + ac;
  const float* bBase = B + (size_t)(bkg * 8) * N + bn0 + bn;

  for (int k0 = 0; k0 < K; k0 += 32) {
    // ---- stage A tile (coalesced float4 x2, convert to bf16) ----
    floatx4 a0 = *(const floatx4*)(aBase + k0);
    floatx4 a1 = *(const floatx4*)(aBase + k0 + 4);
    usx4 ua0 = { f2b(a0.x), f2b(a0.y), f2b(a0.z), f2b(a0.w) };
    usx4 ua1 = { f2b(a1.x), f2b(a1.y), f2b(a1.z), f2b(a1.w) };
    *(usx4*)&As[arow][ac]     = ua0;
    *(usx4*)&As[arow][ac + 4] = ua1;
    // ---- stage B^T tile (8 coalesced dword loads down k, vector LDS write) ----
    const float* bp = bBase + (size_t)k0 * N;
    float bv0 = bp[0];
    float bv1 = bp[(size_t)1 * N];
    float bv2 = bp[(size_t)2 * N];
    float bv3 = bp[(size_t)3 * N];
    float bv4 = bp[(size_t)4 * N];
    float bv5 = bp[(size_t)5 * N];
    float bv6 = bp[(size_t)6 * N];
    float bv7 = bp[(size_t)7 * N];
    usx4 ub0 = { f2b(bv0), f2b(bv1), f2b(bv2), f2b(bv3) };
    usx4 ub1 = { f2b(bv4), f2b(bv5), f2b(bv6), f2b(bv7) };
    *(usx4*)&Bs[bn][bkg*8]     = ub0;
    *(usx4*)&Bs[bn][bkg*8 + 4] = ub1;
    __syncthreads();

    // ---- MFMA: wave computes rows [wave*16, wave*16+16) x all 64 cols ----
    union { usx4 u4[2]; short8 s8; } af, bf;
    af.u4[0] = *(usx4*)&As[wave*16 + l16][quad*8];
    af.u4[1] = *(usx4*)&As[wave*16 + l16][quad*8 + 4];
    #pragma unroll
    for (int tno = 0; tno < 4; ++tno) {
      bf.u4[0] = *(usx4*)&Bs[tno*16 + l16][quad*8];
      bf.u4[1] = *(usx4*)&Bs[tno*16 + l16][quad*8 + 4];
      acc[tno] = __builtin_amdgcn_mfma_f32_16x16x32_bf16(af.s8, bf.s8, acc[tno], 0, 0, 0);
    }
    __syncthreads();
  }

  // ---- epilogue: C/D layout col=lane&15, row=quad*4+reg ----
  #pragma unroll
  for (int tno = 0; tno < 4; ++tno) {
    const int col = bn0 + tno*16 + l16;
    const float bvs = bias[col];
    #pragma unroll
    for (int r = 0; r < 4; ++r) {
      const int row = bm0 + wave*16 + quad*4 + r;
      float v = acc[tno][r] + bvs;
      if (flags & 1) v = gelu_f(v);
      if (flags & 2) v += Res[(size_t)row * N + col];
      C[(size_t)row * N + col] = v;
    }
  }
}

// ---------- MFMA flash attention (causal), bf16 ----------
// grid: (S/64, H, B); block 256 = 4 waves; wave handles 16 q-rows.
// qkv: [B,S,3072] fp32, q at +h*64, k at +1024+h*64, v at +2048+h*64
// out: [B,S,1024] fp32
__global__ __launch_bounds__(256) void attn_mfma_kernel(
    const float* __restrict__ qkv, float* __restrict__ out)
{
  // stride 72 shorts = 144 B: 16B-aligned rows; frag reads spread uniformly
  // over banks (36 words/row, gcd(36,32)=4 -> 8 starts x 8 lanes = minimum).
  __shared__ unsigned short Ks[64][72];  // K tile [key][dh] (also Q staging)
  __shared__ unsigned short Vt[64][72];  // V tile transposed [dh][key]
  __shared__ unsigned short Ps[64][72];  // P per wave: rows [w*16, w*16+16)

  const int t    = threadIdx.x;
  const int wave = t >> 6;
  const int lane = t & 63;
  const int quad = lane >> 4;
  const int l16  = lane & 15;
  const int q0   = blockIdx.x * 64;
  const int h    = blockIdx.y;
  const int b    = blockIdx.z;

  const size_t base = (size_t)b * 2048 * 3072;
  const int qoff = h * 64;
  const int koff = 1024 + h * 64;
  const int voff = 2048 + h * 64;

  // K/Q staging pattern: row = t>>2 (0..63), col chunk = (t&3)*16
  const int srow = t >> 2;
  const int scol = (t & 3) * 16;

  // ---- stage Q (rows q0..q0+63) into Ks, grab per-wave A-fragments ----
  {
    const float* qp = qkv + base + (size_t)(q0 + srow) * 3072 + qoff + scol;
    #pragma unroll
    for (int i = 0; i < 4; ++i) {
      floatx4 v = *(const floatx4*)(qp + i * 4);
      usx4 u = { f2b(v.x), f2b(v.y), f2b(v.z), f2b(v.w) };
      *(usx4*)&Ks[srow][scol + i * 4] = u;
    }
  }
  __syncthreads();
  const short8 qf0 = *(const short8*)&Ks[wave*16 + l16][quad*8];       // dh 0..31
  const short8 qf1 = *(const short8*)&Ks[wave*16 + l16][32 + quad*8];  // dh 32..63

  floatx4 of[4] = {};        // O accum: col = dht*16+l16, row = quad*4+r
  float m[4], l[4];
  #pragma unroll
  for (int r = 0; r < 4; ++r) { m[r] = -1e30f; l[r] = 0.f; }

  const int ntiles = (q0 >> 6) + 1;
  for (int tile = 0; tile < ntiles; ++tile) {
    const int k0 = tile << 6;
    __syncthreads();   // protect Q-frag reads (tile 0) / prev-tile frag reads

    // ---- stage K [key][dh] ----
    {
      const float* kp = qkv + base + (size_t)(k0 + srow) * 3072 + koff + scol;
      #pragma unroll
      for (int i = 0; i < 4; ++i) {
        floatx4 v = *(const floatx4*)(kp + i * 4);
        usx4 u = { f2b(v.x), f2b(v.y), f2b(v.z), f2b(v.w) };
        *(usx4*)&Ks[srow][scol + i * 4] = u;
      }
    }
    // ---- stage V transposed: thread = dh lane, keys wave*16..+16 ----
    {
      const float* vp = qkv + base + (size_t)(k0 + wave*16) * 3072 + voff + lane;
      #pragma unroll
      for (int j = 0; j < 8; ++j) {
        float v0 = vp[(size_t)(2*j)   * 3072];
        float v1 = vp[(size_t)(2*j+1) * 3072];
        unsigned pack = (unsigned)f2b(v0) | ((unsigned)f2b(v1) << 16);
        *(unsigned*)&Vt[lane][wave*16 + 2*j] = pack;
      }
    }
    __syncthreads();

    // ---- S = Q K^T : C[m=q][n=key], 2 MFMAs per 16-key subtile ----
    floatx4 sf[4];
    #pragma unroll
    for (int kt = 0; kt < 4; ++kt) {
      short8 kf0 = *(const short8*)&Ks[kt*16 + l16][quad*8];
      short8 kf1 = *(const short8*)&Ks[kt*16 + l16][32 + quad*8];
      floatx4 z = {};
      z      = __builtin_amdgcn_mfma_f32_16x16x32_bf16(qf0, kf0, z, 0, 0, 0);
      sf[kt] = __builtin_amdgcn_mfma_f32_16x16x32_bf16(qf1, kf1, z, 0, 0, 0);
    }

    // ---- online softmax (rows = quad*4+r; 16 lanes/row, reduce over l16) ----
    const bool lastTile = (tile == ntiles - 1);
    #pragma unroll
    for (int r = 0; r < 4; ++r) {
      const int qrow = q0 + wave*16 + quad*4 + r;
      float sv[4];
      #pragma unroll
      for (int kt = 0; kt < 4; ++kt) {
        sv[kt] = sf[kt][r] * 0.125f;                       // 1/sqrt(64)
        if (lastTile && (k0 + kt*16 + l16 > qrow)) sv[kt] = -1e30f;
      }
      float mx = fmaxf(fmaxf(sv[0], sv[1]), fmaxf(sv[2], sv[3]));
      #pragma unroll
      for (int msk = 1; msk < 16; msk <<= 1) mx = fmaxf(mx, __shfl_xor(mx, msk));
      const float nm = fmaxf(m[r], mx);
      float rs = 0.f;
      unsigned short pb[4];
      #pragma unroll
      for (int kt = 0; kt < 4; ++kt) {
        pb[kt] = f2b(__expf(sv[kt] - nm));
        rs += b2f(pb[kt]);           // denominator matches bf16 numerator
      }
      #pragma unroll
      for (int msk = 1; msk < 16; msk <<= 1) rs += __shfl_xor(rs, msk);
      const float alpha = __expf(m[r] - nm);
      m[r] = nm;
      l[r] = l[r] * alpha + rs;
      #pragma unroll
      for (int dht = 0; dht < 4; ++dht) of[dht][r] *= alpha;
      #pragma unroll
      for (int kt = 0; kt < 4; ++kt)
        Ps[wave*16 + quad*4 + r][kt*16 + l16] = pb[kt];
    }

    // ---- O += P V : A-frag from per-wave Ps, B-frag from Vt ----
    short8 pf0 = *(const short8*)&Ps[wave*16 + l16][quad*8];        // keys 0..31
    short8 pf1 = *(const short8*)&Ps[wave*16 + l16][32 + quad*8];   // keys 32..63
    #pragma unroll
    for (int dht = 0; dht < 4; ++dht) {
      short8 vf0 = *(const short8*)&Vt[dht*16 + l16][quad*8];
      short8 vf1 = *(const short8*)&Vt[dht*16 + l16][32 + quad*8];
      of[dht] = __builtin_amdgcn_mfma_f32_16x16x32_bf16(pf0, vf0, of[dht], 0, 0, 0);
      of[dht] = __builtin_amdgcn_mfma_f32_16x16x32_bf16(pf1, vf1, of[dht], 0, 0, 0);
    }
  }

  // ---- epilogue ----
  #pragma unroll
  for (int r = 0; r < 4; ++r) {
    const float inv = 1.0f / l[r];
    const int qrow = q0 + wave*16 + quad*4 + r;
    float* op = out + ((size_t)b * 2048 + qrow) * 1024 + h * 64 + l16;
    #pragma unroll
    for (int dht = 0; dht < 4; ++dht) op[dht*16] = of[dht][r] * inv;
  }
}

// ---------- launch ----------
extern "C" void kernel_launch(void* const* d_in, const int* in_sizes, int n_in,
                              void* d_out, int out_size, void* d_ws, size_t ws_size,
                              hipStream_t stream) {
  const float* hidden    = (const float*)d_in[0];
  const float* w_attn    = (const float*)d_in[1];
  const float* b_attn    = (const float*)d_in[2];
  const float* w_proj    = (const float*)d_in[3];
  const float* b_proj    = (const float*)d_in[4];
  const float* w_fc      = (const float*)d_in[5];
  const float* b_fc      = (const float*)d_in[6];
  const float* w_fc_proj = (const float*)d_in[7];
  const float* b_fc_proj = (const float*)d_in[8];
  const float* ln1_w     = (const float*)d_in[9];
  const float* ln1_b     = (const float*)d_in[10];
  const float* ln2_w     = (const float*)d_in[11];
  const float* ln2_b     = (const float*)d_in[12];

  float* ws   = (float*)d_ws;
  float* x    = ws;              // 4096*1024
  float* qkv  = ws + 4194304;    // 4096*3072
  float* attn = ws + 16777216;   // 4096*1024
  float* h    = ws + 20971520;   // 4096*1024
  float* fc   = ws + 4194304;    // 4096*4096 (reuses qkv+attn, both dead)
  float* y    = ws;              // reuses x (dead after qkv GEMM)
  float* outp = (float*)d_out;

  // 1) x = LN1(hidden)
  ln_kernel<<<4096, 256, 0, stream>>>(hidden, ln1_w, ln1_b, x);
  // 2) qkv = x @ w_attn + b_attn   [4096,3072]
  gemm_kernel<<<dim3(3072/64, 4096/64), 256, 0, stream>>>(
      x, w_attn, b_attn, nullptr, qkv, 4096, 3072, 1024, 0);
  // 3) attn = softmax(q k^T / 8, causal) v   [4096,1024]
  attn_mfma_kernel<<<dim3(2048/64, 16, 2), 256, 0, stream>>>(qkv, attn);
  // 4) h = hidden + attn @ w_proj + b_proj
  gemm_kernel<<<dim3(1024/64, 4096/64), 256, 0, stream>>>(
      attn, w_proj, b_proj, hidden, h, 4096, 1024, 1024, 2);
  // 5) y = LN2(h)
  ln_kernel<<<4096, 256, 0, stream>>>(h, ln2_w, ln2_b, y);
  // 6) fc = gelu(y @ w_fc + b_fc)   [4096,4096]
  gemm_kernel<<<dim3(4096/64, 4096/64), 256, 0, stream>>>(
      y, w_fc, b_fc, nullptr, fc, 4096, 4096, 1024, 1);
  // 7) out = h + fc @ w_fc_proj + b_fc_proj
  gemm_kernel<<<dim3(1024/64, 4096/64), 256, 0, stream>>>(
      fc, w_fc_proj, b_fc_proj, h, outp, 4096, 1024, 4096, 2);
}

// Round 3
// 483.586 us; speedup vs baseline: 3.0555x; 1.4072x over previous
//
#include <hip/hip_runtime.h>
#include <cstdint>
#include <cstddef>

// ---------- types ----------
typedef unsigned short u16;
typedef float  floatx4 __attribute__((ext_vector_type(4)));
typedef short  short8  __attribute__((ext_vector_type(8)));
typedef u16    usx4    __attribute__((ext_vector_type(4)));
typedef u16    usx8    __attribute__((ext_vector_type(8)));

// fp32 -> bf16, round-to-nearest-even
__device__ __forceinline__ u16 f2b(float f) {
  unsigned u = __float_as_uint(f);
  unsigned r = u + 0x7fffu + ((u >> 16) & 1u);
  return (u16)(r >> 16);
}
__device__ __forceinline__ float b2f(u16 s) {
  return __uint_as_float(((unsigned)s) << 16);
}

__device__ __forceinline__ float gelu_f(float x) {
  const float c = 0.7978845608028654f; // sqrt(2/pi)
  float t = tanhf(c * (x + 0.044715f * x * x * x));
  return 0.5f * x * (1.0f + t);
}

// async global->LDS 16B: lds dst must be wave-uniform base (+ lane*16 by HW)
__device__ __forceinline__ void gl2lds16(const u16* g, u16* l) {
  __builtin_amdgcn_global_load_lds(
      (const __attribute__((address_space(1))) unsigned int*)g,
      (__attribute__((address_space(3))) unsigned int*)l, 16, 0, 0);
}

// ---------- LayerNorm: one block per row of 1024, bf16 out ----------
__global__ __launch_bounds__(256) void ln_bf16_kernel(
    const float* __restrict__ in, const float* __restrict__ w,
    const float* __restrict__ b, u16* __restrict__ out)
{
  const int row = blockIdx.x;
  const int t = threadIdx.x;
  const float* p = in + (size_t)row * 1024 + t * 4;
  floatx4 v = *(const floatx4*)p;
  float s  = v.x + v.y + v.z + v.w;
  float ss = v.x*v.x + v.y*v.y + v.z*v.z + v.w*v.w;
  #pragma unroll
  for (int m = 1; m < 64; m <<= 1) {
    s  += __shfl_xor(s,  m);
    ss += __shfl_xor(ss, m);
  }
  __shared__ float red[8];
  if ((t & 63) == 0) { red[(t >> 6)*2] = s; red[(t >> 6)*2 + 1] = ss; }
  __syncthreads();
  s  = red[0] + red[2] + red[4] + red[6];
  ss = red[1] + red[3] + red[5] + red[7];
  const float mean = s * (1.0f / 1024.0f);
  const float var  = ss * (1.0f / 1024.0f) - mean * mean;
  const float rstd = rsqrtf(var + 1e-6f);
  floatx4 wv = *(const floatx4*)(w + t * 4);
  floatx4 bv = *(const floatx4*)(b + t * 4);
  usx4 o = { f2b(wv.x * ((v.x - mean) * rstd) + bv.x),
             f2b(wv.y * ((v.y - mean) * rstd) + bv.y),
             f2b(wv.z * ((v.z - mean) * rstd) + bv.z),
             f2b(wv.w * ((v.w - mean) * rstd) + bv.w) };
  *(usx4*)(out + (size_t)row * 1024 + t * 4) = o;
}

// ---------- weight transpose+convert: in[K,N] fp32 -> out[N,K] bf16 ----------
__global__ __launch_bounds__(256) void wtrans_kernel(
    const float* __restrict__ in, u16* __restrict__ out, int K, int N)
{
  __shared__ u16 tile[32][33];
  const int n0 = blockIdx.x * 32, k0 = blockIdx.y * 32;
  const int tx = threadIdx.x & 31, ty = threadIdx.x >> 5;  // ty 0..7
  #pragma unroll
  for (int i = 0; i < 4; ++i)
    tile[ty + i*8][tx] = f2b(in[(size_t)(k0 + ty + i*8) * N + n0 + tx]);
  __syncthreads();
  #pragma unroll
  for (int i = 0; i < 4; ++i)
    out[(size_t)(n0 + ty + i*8) * K + k0 + tx] = tile[tx][ty + i*8];
}

// ---------- GEMM (m97 structure): C[M,N] = A[M,K] @ Bt[N,K]^T ----------
// BMxBN tile, BK=32, 256 threads, 4 waves 2x2, global_load_lds(16B) staging,
// chunk-XOR swizzle -> 2-way (free) LDS bank pattern on frag reads.
// FLAGS: 1 = gelu, 2 = +Res (fp32), 4 = bf16 out
template<int BM, int BN, int FLAGS>
__global__ __launch_bounds__(256) void gemm_mfma_kernel(
    const u16* __restrict__ A, const u16* __restrict__ Bt,
    const float* __restrict__ bias, const float* __restrict__ Res,
    void* __restrict__ Cout, int M, int N, int K)
{
  constexpr int WM = BM / 2, WN = BN / 2;
  constexpr int MT = WM / 16, NT = WN / 16;
  __shared__ u16 As[BM * 32];
  __shared__ u16 Bs[BN * 32];

  const int t = threadIdx.x;
  const int wave = t >> 6, lane = t & 63;
  const int quad = lane >> 4, l16 = lane & 15;
  const int wm = wave >> 1, wn = wave & 1;
  const int bm0 = blockIdx.y * BM, bn0 = blockIdx.x * BN;

  // staging: wave w + iter j covers 16 rows (1024 B of LDS), lane i -> row
  // band+i/4, chunk position i&3; fetch swizzled global chunk (i&3)^((i>>3)&3)
  const int sRow = lane >> 2;
  const int sq   = (lane & 3) ^ ((lane >> 3) & 3);

  const u16* aG[BM / 64];
  u16* aL[BM / 64];
  #pragma unroll
  for (int j = 0; j < BM / 64; ++j) {
    const int band = j * 4 + wave;
    aG[j] = A + (size_t)(bm0 + band * 16 + sRow) * K + sq * 8;
    aL[j] = As + band * 512;
  }
  const u16* bG[BN / 64];
  u16* bL[BN / 64];
  #pragma unroll
  for (int j = 0; j < BN / 64; ++j) {
    const int band = j * 4 + wave;
    bG[j] = Bt + (size_t)(bn0 + band * 16 + sRow) * K + sq * 8;
    bL[j] = Bs + band * 512;
  }

  floatx4 acc[MT][NT] = {};
  const int sR = (l16 >> 1) & 3;   // read-side swizzle key

  for (int k0 = 0; k0 < K; k0 += 32) {
    __syncthreads();
    #pragma unroll
    for (int j = 0; j < BM / 64; ++j) gl2lds16(aG[j] + k0, aL[j]);
    #pragma unroll
    for (int j = 0; j < BN / 64; ++j) gl2lds16(bG[j] + k0, bL[j]);
    __syncthreads();

    short8 af[MT], bf[NT];
    #pragma unroll
    for (int mt = 0; mt < MT; ++mt)
      af[mt] = *(const short8*)&As[(wm*WM + mt*16 + l16) * 32 + ((quad ^ sR) << 3)];
    #pragma unroll
    for (int nt = 0; nt < NT; ++nt)
      bf[nt] = *(const short8*)&Bs[(wn*WN + nt*16 + l16) * 32 + ((quad ^ sR) << 3)];
    #pragma unroll
    for (int mt = 0; mt < MT; ++mt)
      #pragma unroll
      for (int nt = 0; nt < NT; ++nt)
        acc[mt][nt] = __builtin_amdgcn_mfma_f32_16x16x32_bf16(af[mt], bf[nt], acc[mt][nt], 0, 0, 0);
  }

  // epilogue: C/D layout col=lane&15, row=quad*4+reg
  const int orow0 = bm0 + wm * WM;
  const int ocol0 = bn0 + wn * WN;
  #pragma unroll
  for (int nt = 0; nt < NT; ++nt) {
    const int col = ocol0 + nt*16 + l16;
    const float bv = bias[col];
    #pragma unroll
    for (int mt = 0; mt < MT; ++mt) {
      #pragma unroll
      for (int r = 0; r < 4; ++r) {
        const int row = orow0 + mt*16 + quad*4 + r;
        float v = acc[mt][nt][r] + bv;
        if (FLAGS & 1) v = gelu_f(v);
        if (FLAGS & 2) v += Res[(size_t)row * N + col];
        if (FLAGS & 4) ((u16*)Cout)[(size_t)row * N + col] = f2b(v);
        else           ((float*)Cout)[(size_t)row * N + col] = v;
      }
    }
  }
}

// ---------- MFMA flash attention (causal), bf16 in/out ----------
// grid: (S/64, H, B); block 256 = 4 waves; wave handles 16 q-rows.
// qkv: [B,S,3072] bf16; out: [B,S,1024] bf16
__global__ __launch_bounds__(256) void attn_mfma_kernel(
    const u16* __restrict__ qkv, u16* __restrict__ out)
{
  __shared__ u16 Ks[64][72];  // K tile [key][dh] (also Q staging)
  __shared__ u16 Vt[64][72];  // V tile transposed [dh][key]
  __shared__ u16 Ps[64][72];  // P per wave: rows [w*16, w*16+16)

  const int t    = threadIdx.x;
  const int wave = t >> 6;
  const int lane = t & 63;
  const int quad = lane >> 4;
  const int l16  = lane & 15;
  const int q0   = blockIdx.x * 64;
  const int h    = blockIdx.y;
  const int b    = blockIdx.z;

  const size_t base = (size_t)b * 2048 * 3072;
  const int qoff = h * 64;
  const int koff = 1024 + h * 64;
  const int voff = 2048 + h * 64;

  const int srow = t >> 2;
  const int scol = (t & 3) * 16;

  // ---- stage Q into Ks, grab per-wave A-fragments ----
  {
    const u16* qp = qkv + base + (size_t)(q0 + srow) * 3072 + qoff + scol;
    *(usx8*)&Ks[srow][scol]     = *(const usx8*)qp;
    *(usx8*)&Ks[srow][scol + 8] = *(const usx8*)(qp + 8);
  }
  __syncthreads();
  const short8 qf0 = *(const short8*)&Ks[wave*16 + l16][quad*8];       // dh 0..31
  const short8 qf1 = *(const short8*)&Ks[wave*16 + l16][32 + quad*8];  // dh 32..63

  floatx4 of[4] = {};
  float m[4], l[4];
  #pragma unroll
  for (int r = 0; r < 4; ++r) { m[r] = -1e30f; l[r] = 0.f; }

  const int ntiles = (q0 >> 6) + 1;
  for (int tile = 0; tile < ntiles; ++tile) {
    const int k0 = tile << 6;
    __syncthreads();

    // ---- stage K [key][dh] ----
    {
      const u16* kp = qkv + base + (size_t)(k0 + srow) * 3072 + koff + scol;
      *(usx8*)&Ks[srow][scol]     = *(const usx8*)kp;
      *(usx8*)&Ks[srow][scol + 8] = *(const usx8*)(kp + 8);
    }
    // ---- stage V transposed: thread = dh lane, keys wave*16..+16 ----
    {
      const u16* vp = qkv + base + (size_t)(k0 + wave*16) * 3072 + voff + lane;
      #pragma unroll
      for (int j = 0; j < 8; ++j) {
        unsigned v0 = vp[(size_t)(2*j)   * 3072];
        unsigned v1 = vp[(size_t)(2*j+1) * 3072];
        *(unsigned*)&Vt[lane][wave*16 + 2*j] = v0 | (v1 << 16);
      }
    }
    __syncthreads();

    // ---- S = Q K^T ----
    floatx4 sf[4];
    #pragma unroll
    for (int kt = 0; kt < 4; ++kt) {
      short8 kf0 = *(const short8*)&Ks[kt*16 + l16][quad*8];
      short8 kf1 = *(const short8*)&Ks[kt*16 + l16][32 + quad*8];
      floatx4 z = {};
      z      = __builtin_amdgcn_mfma_f32_16x16x32_bf16(qf0, kf0, z, 0, 0, 0);
      sf[kt] = __builtin_amdgcn_mfma_f32_16x16x32_bf16(qf1, kf1, z, 0, 0, 0);
    }

    // ---- online softmax ----
    const bool lastTile = (tile == ntiles - 1);
    #pragma unroll
    for (int r = 0; r < 4; ++r) {
      const int qrow = q0 + wave*16 + quad*4 + r;
      float sv[4];
      #pragma unroll
      for (int kt = 0; kt < 4; ++kt) {
        sv[kt] = sf[kt][r] * 0.125f;
        if (lastTile && (k0 + kt*16 + l16 > qrow)) sv[kt] = -1e30f;
      }
      float mx = fmaxf(fmaxf(sv[0], sv[1]), fmaxf(sv[2], sv[3]));
      #pragma unroll
      for (int msk = 1; msk < 16; msk <<= 1) mx = fmaxf(mx, __shfl_xor(mx, msk));
      const float nm = fmaxf(m[r], mx);
      float rs = 0.f;
      u16 pb[4];
      #pragma unroll
      for (int kt = 0; kt < 4; ++kt) {
        pb[kt] = f2b(__expf(sv[kt] - nm));
        rs += b2f(pb[kt]);
      }
      #pragma unroll
      for (int msk = 1; msk < 16; msk <<= 1) rs += __shfl_xor(rs, msk);
      const float alpha = __expf(m[r] - nm);
      m[r] = nm;
      l[r] = l[r] * alpha + rs;
      #pragma unroll
      for (int dht = 0; dht < 4; ++dht) of[dht][r] *= alpha;
      #pragma unroll
      for (int kt = 0; kt < 4; ++kt)
        Ps[wave*16 + quad*4 + r][kt*16 + l16] = pb[kt];
    }

    // ---- O += P V ----
    short8 pf0 = *(const short8*)&Ps[wave*16 + l16][quad*8];
    short8 pf1 = *(const short8*)&Ps[wave*16 + l16][32 + quad*8];
    #pragma unroll
    for (int dht = 0; dht < 4; ++dht) {
      short8 vf0 = *(const short8*)&Vt[dht*16 + l16][quad*8];
      short8 vf1 = *(const short8*)&Vt[dht*16 + l16][32 + quad*8];
      of[dht] = __builtin_amdgcn_mfma_f32_16x16x32_bf16(pf0, vf0, of[dht], 0, 0, 0);
      of[dht] = __builtin_amdgcn_mfma_f32_16x16x32_bf16(pf1, vf1, of[dht], 0, 0, 0);
    }
  }

  // ---- epilogue: bf16 out ----
  #pragma unroll
  for (int r = 0; r < 4; ++r) {
    const float inv = 1.0f / l[r];
    const int qrow = q0 + wave*16 + quad*4 + r;
    u16* op = out + ((size_t)b * 2048 + qrow) * 1024 + h * 64 + l16;
    #pragma unroll
    for (int dht = 0; dht < 4; ++dht) op[dht*16] = f2b(of[dht][r] * inv);
  }
}

// ---------- launch ----------
extern "C" void kernel_launch(void* const* d_in, const int* in_sizes, int n_in,
                              void* d_out, int out_size, void* d_ws, size_t ws_size,
                              hipStream_t stream) {
  const float* hidden    = (const float*)d_in[0];
  const float* w_attn    = (const float*)d_in[1];
  const float* b_attn    = (const float*)d_in[2];
  const float* w_proj    = (const float*)d_in[3];
  const float* b_proj    = (const float*)d_in[4];
  const float* w_fc      = (const float*)d_in[5];
  const float* b_fc      = (const float*)d_in[6];
  const float* w_fc_proj = (const float*)d_in[7];
  const float* b_fc_proj = (const float*)d_in[8];
  const float* ln1_w     = (const float*)d_in[9];
  const float* ln1_b     = (const float*)d_in[10];
  const float* ln2_w     = (const float*)d_in[11];
  const float* ln2_b     = (const float*)d_in[12];

  char* wsb = (char*)d_ws;
  u16*   xb    = (u16*)  (wsb + (size_t)( 0u << 20));  //  8 MB [4096,1024]
  u16*   qkvb  = (u16*)  (wsb + (size_t)( 8u << 20));  // 24 MB [4096,3072]
  u16*   attnb = (u16*)  (wsb + (size_t)(32u << 20));  //  8 MB [4096,1024]
  float* hbuf  = (float*)(wsb + (size_t)(40u << 20));  // 16 MB [4096,1024] fp32
  u16*   wqT   = (u16*)  (wsb + (size_t)(56u << 20));  //  6 MB [3072,1024]
  u16*   wpT   = (u16*)  (wsb + (size_t)(62u << 20));  //  2 MB [1024,1024]
  u16*   wfT   = (u16*)  (wsb + (size_t)(64u << 20));  //  8 MB [4096,1024]
  u16*   wfpT  = (u16*)  (wsb + (size_t)(72u << 20));  //  8 MB [1024,4096]
  u16*   fcb   = qkvb;   // 32 MB [4096,4096], reuses qkvb+attnb (dead)
  u16*   yb    = xb;     // reuses xb (dead after qkv GEMM)

  // 0) weight transpose+convert fp32[K,N] -> bf16[N,K]
  wtrans_kernel<<<dim3(96, 32),  256, 0, stream>>>(w_attn,    wqT,  1024, 3072);
  wtrans_kernel<<<dim3(32, 32),  256, 0, stream>>>(w_proj,    wpT,  1024, 1024);
  wtrans_kernel<<<dim3(128, 32), 256, 0, stream>>>(w_fc,      wfT,  1024, 4096);
  wtrans_kernel<<<dim3(32, 128), 256, 0, stream>>>(w_fc_proj, wfpT, 4096, 1024);

  // 1) x = LN1(hidden) -> bf16
  ln_bf16_kernel<<<4096, 256, 0, stream>>>(hidden, ln1_w, ln1_b, xb);
  // 2) qkv = x @ w_attn + b_attn -> bf16 [4096,3072]
  gemm_mfma_kernel<128,128,4><<<dim3(24, 32), 256, 0, stream>>>(
      xb, wqT, b_attn, nullptr, qkvb, 4096, 3072, 1024);
  // 3) attn = flash(qkv) -> bf16 [4096,1024]
  attn_mfma_kernel<<<dim3(32, 16, 2), 256, 0, stream>>>(qkvb, attnb);
  // 4) h = hidden + attn @ w_proj + b_proj -> fp32
  gemm_mfma_kernel<128,64,2><<<dim3(16, 32), 256, 0, stream>>>(
      attnb, wpT, b_proj, hidden, hbuf, 4096, 1024, 1024);
  // 5) y = LN2(h) -> bf16
  ln_bf16_kernel<<<4096, 256, 0, stream>>>(hbuf, ln2_w, ln2_b, yb);
  // 6) fc = gelu(y @ w_fc + b_fc) -> bf16 [4096,4096]
  gemm_mfma_kernel<128,128,5><<<dim3(32, 32), 256, 0, stream>>>(
      yb, wfT, b_fc, nullptr, fcb, 4096, 4096, 1024);
  // 7) out = h + fc @ w_fc_proj + b_fc_proj -> fp32
  gemm_mfma_kernel<128,64,2><<<dim3(16, 32), 256, 0, stream>>>(
      fcb, wfpT, b_fc_proj, hbuf, (float*)d_out, 4096, 1024, 4096);
}

// Round 4
// 405.660 us; speedup vs baseline: 3.6425x; 1.1921x over previous
//
#include <hip/hip_runtime.h>
#include <cstdint>
#include <cstddef>

// ---------- types ----------
typedef unsigned short u16;
typedef float  floatx4 __attribute__((ext_vector_type(4)));
typedef short  short8  __attribute__((ext_vector_type(8)));
typedef u16    usx4    __attribute__((ext_vector_type(4)));
typedef u16    usx8    __attribute__((ext_vector_type(8)));

// fp32 -> bf16, round-to-nearest-even
__device__ __forceinline__ u16 f2b(float f) {
  unsigned u = __float_as_uint(f);
  unsigned r = u + 0x7fffu + ((u >> 16) & 1u);
  return (u16)(r >> 16);
}
__device__ __forceinline__ float b2f(u16 s) {
  return __uint_as_float(((unsigned)s) << 16);
}

__device__ __forceinline__ float gelu_f(float x) {
  const float c = 0.7978845608028654f; // sqrt(2/pi)
  float t = tanhf(c * (x + 0.044715f * x * x * x));
  return 0.5f * x * (1.0f + t);
}

// async global->LDS 16B: lds dst = wave-uniform base + lane*16 (HW rule)
__device__ __forceinline__ void gl2lds16(const u16* g, u16* l) {
  __builtin_amdgcn_global_load_lds(
      (const __attribute__((address_space(1))) unsigned int*)g,
      (__attribute__((address_space(3))) unsigned int*)l, 16, 0, 0);
}

// ---------- LayerNorm: one block per row of 1024, bf16 out ----------
__global__ __launch_bounds__(256) void ln_bf16_kernel(
    const float* __restrict__ in, const float* __restrict__ w,
    const float* __restrict__ b, u16* __restrict__ out)
{
  const int row = blockIdx.x;
  const int t = threadIdx.x;
  const float* p = in + (size_t)row * 1024 + t * 4;
  floatx4 v = *(const floatx4*)p;
  float s  = v.x + v.y + v.z + v.w;
  float ss = v.x*v.x + v.y*v.y + v.z*v.z + v.w*v.w;
  #pragma unroll
  for (int m = 1; m < 64; m <<= 1) {
    s  += __shfl_xor(s,  m);
    ss += __shfl_xor(ss, m);
  }
  __shared__ float red[8];
  if ((t & 63) == 0) { red[(t >> 6)*2] = s; red[(t >> 6)*2 + 1] = ss; }
  __syncthreads();
  s  = red[0] + red[2] + red[4] + red[6];
  ss = red[1] + red[3] + red[5] + red[7];
  const float mean = s * (1.0f / 1024.0f);
  const float var  = ss * (1.0f / 1024.0f) - mean * mean;
  const float rstd = rsqrtf(var + 1e-6f);
  floatx4 wv = *(const floatx4*)(w + t * 4);
  floatx4 bv = *(const floatx4*)(b + t * 4);
  usx4 o = { f2b(wv.x * ((v.x - mean) * rstd) + bv.x),
             f2b(wv.y * ((v.y - mean) * rstd) + bv.y),
             f2b(wv.z * ((v.z - mean) * rstd) + bv.z),
             f2b(wv.w * ((v.w - mean) * rstd) + bv.w) };
  *(usx4*)(out + (size_t)row * 1024 + t * 4) = o;
}

// ---------- weight transpose+convert: in[K,N] fp32 -> out[N,K] bf16 ----------
__global__ __launch_bounds__(256) void wtrans_kernel(
    const float* __restrict__ in, u16* __restrict__ out, int K, int N)
{
  __shared__ u16 tile[32][33];
  const int n0 = blockIdx.x * 32, k0 = blockIdx.y * 32;
  const int tx = threadIdx.x & 31, ty = threadIdx.x >> 5;  // ty 0..7
  #pragma unroll
  for (int i = 0; i < 4; ++i)
    tile[ty + i*8][tx] = f2b(in[(size_t)(k0 + ty + i*8) * N + n0 + tx]);
  __syncthreads();
  #pragma unroll
  for (int i = 0; i < 4; ++i)
    out[(size_t)(n0 + ty + i*8) * K + k0 + tx] = tile[tx][ty + i*8];
}

// ---------- GEMM (m97 structure): C[M,N] = A[M,K] @ Bt[N,K]^T ----------
// BMxBN tile, BK=32, 256 threads, 4 waves 2x2, global_load_lds(16B) staging.
// grid.z splits K: kStart = z*kLen; bf16 partial outputs offset by z*M*N.
// FLAGS: 1 = gelu, 2 = +Res (fp32), 4 = bf16 out
template<int BM, int BN, int FLAGS, int MINW>
__global__ __launch_bounds__(256, MINW) void gemm_mfma_kernel(
    const u16* __restrict__ A, const u16* __restrict__ Bt,
    const float* __restrict__ bias, const float* __restrict__ Res,
    void* __restrict__ Cout, int M, int N, int K, int kLen)
{
  constexpr int WM = BM / 2, WN = BN / 2;
  constexpr int MT = WM / 16, NT = WN / 16;
  __shared__ u16 As[BM * 32];
  __shared__ u16 Bs[BN * 32];

  const int t = threadIdx.x;
  const int wave = t >> 6, lane = t & 63;
  const int quad = lane >> 4, l16 = lane & 15;
  const int wm = wave >> 1, wn = wave & 1;
  const int bm0 = blockIdx.y * BM, bn0 = blockIdx.x * BN;
  const int kStart = blockIdx.z * kLen;

  // staging: wave w + iter j covers 16 rows (1024 B of LDS), lane -> row lane/4,
  // 16B chunk (lane&3)
  const int sRow = lane >> 2;
  const int sq   = lane & 3;

  const u16* aG[BM / 64];
  u16* aL[BM / 64];
  #pragma unroll
  for (int j = 0; j < BM / 64; ++j) {
    const int band = j * 4 + wave;
    aG[j] = A + (size_t)(bm0 + band * 16 + sRow) * K + kStart + sq * 8;
    aL[j] = As + band * 512;
  }
  const u16* bG[BN / 64];
  u16* bL[BN / 64];
  #pragma unroll
  for (int j = 0; j < BN / 64; ++j) {
    const int band = j * 4 + wave;
    bG[j] = Bt + (size_t)(bn0 + band * 16 + sRow) * K + kStart + sq * 8;
    bL[j] = Bs + band * 512;
  }

  floatx4 acc[MT][NT] = {};

  for (int k0 = 0; k0 < kLen; k0 += 32) {
    __syncthreads();
    #pragma unroll
    for (int j = 0; j < BM / 64; ++j) gl2lds16(aG[j] + k0, aL[j]);
    #pragma unroll
    for (int j = 0; j < BN / 64; ++j) gl2lds16(bG[j] + k0, bL[j]);
    __syncthreads();

    short8 af[MT], bf[NT];
    #pragma unroll
    for (int mt = 0; mt < MT; ++mt)
      af[mt] = *(const short8*)&As[(wm*WM + mt*16 + l16) * 32 + quad * 8];
    #pragma unroll
    for (int nt = 0; nt < NT; ++nt)
      bf[nt] = *(const short8*)&Bs[(wn*WN + nt*16 + l16) * 32 + quad * 8];
    #pragma unroll
    for (int mt = 0; mt < MT; ++mt)
      #pragma unroll
      for (int nt = 0; nt < NT; ++nt)
        acc[mt][nt] = __builtin_amdgcn_mfma_f32_16x16x32_bf16(af[mt], bf[nt], acc[mt][nt], 0, 0, 0);
  }

  // epilogue: C/D layout col=lane&15, row=quad*4+reg
  const int orow0 = bm0 + wm * WM;
  const int ocol0 = bn0 + wn * WN;
  const size_t zoff = (size_t)blockIdx.z * M * N;
  #pragma unroll
  for (int nt = 0; nt < NT; ++nt) {
    const int col = ocol0 + nt*16 + l16;
    const float bv = bias ? bias[col] : 0.0f;
    #pragma unroll
    for (int mt = 0; mt < MT; ++mt) {
      #pragma unroll
      for (int r = 0; r < 4; ++r) {
        const int row = orow0 + mt*16 + quad*4 + r;
        float v = acc[mt][nt][r] + bv;
        if (FLAGS & 1) v = gelu_f(v);
        if (FLAGS & 2) v += Res[(size_t)row * N + col];
        if (FLAGS & 4) ((u16*)Cout)[zoff + (size_t)row * N + col] = f2b(v);
        else           ((float*)Cout)[zoff + (size_t)row * N + col] = v;
      }
    }
  }
}

// ---------- MFMA flash attention (causal), bf16, balanced + K-split ----------
// grid: (32, H, B): u = blockIdx.x -> pair = u>>1 (0..15), half = u&1.
// Block processes q-tiles {pair, 31-pair} (64 rows each), key partition `half`.
// Writes UNNORMALIZED partial O (bf16) + per-row (m, l) in log2 domain.
// opart: [part][b][h][2048][64] bf16 ; ml: [part][b][h][2048][2] fp32
__global__ __launch_bounds__(256, 4) void attn_mfma_kernel(
    const u16* __restrict__ qkv, u16* __restrict__ opart, float* __restrict__ ml)
{
  __shared__ u16 Ks[64][72];  // K tile [key][dh] (also Q staging)
  __shared__ u16 Vt[64][72];  // V tile transposed [dh][key]
  __shared__ u16 Ps[64][72];  // P per wave: rows [w*16, w*16+16)

  const int t    = threadIdx.x;
  const int wave = t >> 6;
  const int lane = t & 63;
  const int quad = lane >> 4;
  const int l16  = lane & 15;
  const int pair = blockIdx.x >> 1;
  const int half = blockIdx.x & 1;
  const int h    = blockIdx.y;
  const int b    = blockIdx.z;

  const size_t base = (size_t)b * 2048 * 3072;
  const int qoff = h * 64;
  const int koff = 1024 + h * 64;
  const int voff = 2048 + h * 64;

  const int srow = t >> 2;          // K/Q staging row
  const int scol = (t & 3) * 16;    // K/Q staging col chunk
  const int kpair  = t & 31;        // V staging: keys 2*kpair, 2*kpair+1
  const int vchunk = t >> 5;        // V staging: dh chunk (0..7)

  const size_t obase  = ((((size_t)half * 2 + b) * 16 + h) * 2048) * 64;
  const size_t mlbase = ((((size_t)half * 2 + b) * 16 + h) * 2048) * 2;

  const float C2 = 0.18033688011112042f;  // (1/8) * log2(e)

  #pragma unroll 1
  for (int iter = 0; iter < 2; ++iter) {
    const int qi = iter ? (31 - pair) : pair;
    const int q0 = qi << 6;
    const int T  = qi + 1;
    const int mid = (T + 1) >> 1;
    const int t0 = half ? mid : 0;
    const int t1 = half ? T : mid;

    floatx4 of[4] = {};
    float m[4], l[4];
    #pragma unroll
    for (int r = 0; r < 4; ++r) { m[r] = -1e30f; l[r] = 0.f; }

    if (t0 < t1) {
      // ---- stage Q into Ks, grab per-wave A-fragments ----
      __syncthreads();
      {
        const u16* qp = qkv + base + (size_t)(q0 + srow) * 3072 + qoff + scol;
        *(usx8*)&Ks[srow][scol]     = *(const usx8*)qp;
        *(usx8*)&Ks[srow][scol + 8] = *(const usx8*)(qp + 8);
      }
      __syncthreads();
      const short8 qf0 = *(const short8*)&Ks[wave*16 + l16][quad*8];
      const short8 qf1 = *(const short8*)&Ks[wave*16 + l16][32 + quad*8];

      // ---- prefetch first K/V tile into regs ----
      usx8 kr0, kr1, vr0, vr1;
      {
        const int k0 = t0 << 6;
        const u16* kp = qkv + base + (size_t)(k0 + srow) * 3072 + koff + scol;
        kr0 = *(const usx8*)kp; kr1 = *(const usx8*)(kp + 8);
        const u16* vp = qkv + base + (size_t)(k0 + 2*kpair) * 3072 + voff + vchunk*8;
        vr0 = *(const usx8*)vp; vr1 = *(const usx8*)(vp + 3072);
      }

      for (int tIdx = t0; tIdx < t1; ++tIdx) {
        __syncthreads();   // all frag reads of previous contents done
        // ---- write staged regs to LDS ----
        *(usx8*)&Ks[srow][scol]     = kr0;
        *(usx8*)&Ks[srow][scol + 8] = kr1;
        #pragma unroll
        for (int i = 0; i < 8; ++i)
          *(unsigned*)&Vt[vchunk*8 + i][2*kpair] =
              (unsigned)vr0[i] | ((unsigned)vr1[i] << 16);
        __syncthreads();

        // ---- prefetch next tile (overlaps compute) ----
        if (tIdx + 1 < t1) {
          const int kn = (tIdx + 1) << 6;
          const u16* kp = qkv + base + (size_t)(kn + srow) * 3072 + koff + scol;
          kr0 = *(const usx8*)kp; kr1 = *(const usx8*)(kp + 8);
          const u16* vp = qkv + base + (size_t)(kn + 2*kpair) * 3072 + voff + vchunk*8;
          vr0 = *(const usx8*)vp; vr1 = *(const usx8*)(vp + 3072);
        }

        // ---- S = Q K^T ----
        const int k0 = tIdx << 6;
        floatx4 sf[4];
        #pragma unroll
        for (int kt = 0; kt < 4; ++kt) {
          short8 kf0 = *(const short8*)&Ks[kt*16 + l16][quad*8];
          short8 kf1 = *(const short8*)&Ks[kt*16 + l16][32 + quad*8];
          floatx4 z = {};
          z      = __builtin_amdgcn_mfma_f32_16x16x32_bf16(qf0, kf0, z, 0, 0, 0);
          sf[kt] = __builtin_amdgcn_mfma_f32_16x16x32_bf16(qf1, kf1, z, 0, 0, 0);
        }

        // ---- online softmax (log2 domain, exp2 native) ----
        const bool diag = (tIdx == qi);
        #pragma unroll
        for (int r = 0; r < 4; ++r) {
          const int qrow = q0 + wave*16 + quad*4 + r;
          float sv[4];
          #pragma unroll
          for (int kt = 0; kt < 4; ++kt) {
            sv[kt] = sf[kt][r] * C2;
            if (diag && (k0 + kt*16 + l16 > qrow)) sv[kt] = -1e30f;
          }
          float mx = fmaxf(fmaxf(sv[0], sv[1]), fmaxf(sv[2], sv[3]));
          #pragma unroll
          for (int msk = 1; msk < 16; msk <<= 1) mx = fmaxf(mx, __shfl_xor(mx, msk));
          const float nm = fmaxf(m[r], mx);
          float rs = 0.f;
          u16 pb[4];
          #pragma unroll
          for (int kt = 0; kt < 4; ++kt) {
            pb[kt] = f2b(exp2f(sv[kt] - nm));
            rs += b2f(pb[kt]);        // denominator matches bf16 numerator
          }
          #pragma unroll
          for (int msk = 1; msk < 16; msk <<= 1) rs += __shfl_xor(rs, msk);
          const float alpha = exp2f(m[r] - nm);
          m[r] = nm;
          l[r] = l[r] * alpha + rs;
          #pragma unroll
          for (int dht = 0; dht < 4; ++dht) of[dht][r] *= alpha;
          #pragma unroll
          for (int kt = 0; kt < 4; ++kt)
            Ps[wave*16 + quad*4 + r][kt*16 + l16] = pb[kt];
        }

        // ---- O += P V ----
        short8 pf0 = *(const short8*)&Ps[wave*16 + l16][quad*8];
        short8 pf1 = *(const short8*)&Ps[wave*16 + l16][32 + quad*8];
        #pragma unroll
        for (int dht = 0; dht < 4; ++dht) {
          short8 vf0 = *(const short8*)&Vt[dht*16 + l16][quad*8];
          short8 vf1 = *(const short8*)&Vt[dht*16 + l16][32 + quad*8];
          of[dht] = __builtin_amdgcn_mfma_f32_16x16x32_bf16(pf0, vf0, of[dht], 0, 0, 0);
          of[dht] = __builtin_amdgcn_mfma_f32_16x16x32_bf16(pf1, vf1, of[dht], 0, 0, 0);
        }
      }
    }

    // ---- write partial (unnormalized O + m,l); zeros if empty range ----
    #pragma unroll
    for (int r = 0; r < 4; ++r) {
      const int s = q0 + wave*16 + quad*4 + r;
      u16* orow = opart + obase + (size_t)s * 64;
      #pragma unroll
      for (int dht = 0; dht < 4; ++dht) orow[dht*16 + l16] = f2b(of[dht][r]);
      if (l16 == 0) { ml[mlbase + 2*s] = m[r]; ml[mlbase + 2*s + 1] = l[r]; }
    }
  }
}

// ---------- combine attention partials -> attnb bf16 [B,S,1024] ----------
// grid (512, H, B), block 256: wave -> row, lane -> dh
__global__ __launch_bounds__(256) void attn_combine_kernel(
    const u16* __restrict__ opart, const float* __restrict__ ml,
    u16* __restrict__ out)
{
  const int t = threadIdx.x;
  const int s = blockIdx.x * 4 + (t >> 6);
  const int lane = t & 63;
  const int h = blockIdx.y, b = blockIdx.z;

  const size_t o0  = ((((size_t)0 * 2 + b) * 16 + h) * 2048 + s) * 64 + lane;
  const size_t o1  = ((((size_t)1 * 2 + b) * 16 + h) * 2048 + s) * 64 + lane;
  const size_t ml0 = ((((size_t)0 * 2 + b) * 16 + h) * 2048 + s) * 2;
  const size_t ml1 = ((((size_t)1 * 2 + b) * 16 + h) * 2048 + s) * 2;

  const float m0 = ml[ml0], l0 = ml[ml0 + 1];
  const float m1 = ml[ml1], l1 = ml[ml1 + 1];
  const float M  = fmaxf(m0, m1);
  const float w0 = exp2f(m0 - M), w1 = exp2f(m1 - M);
  const float L  = w0 * l0 + w1 * l1;
  const float o  = w0 * b2f(opart[o0]) + w1 * b2f(opart[o1]);
  out[((size_t)b * 2048 + s) * 1024 + h * 64 + lane] = f2b(o / L);
}

// ---------- fc_proj K-split combine: out = hbuf + p0 + p1 + bias ----------
__global__ __launch_bounds__(256) void fcproj_combine_kernel(
    const u16* __restrict__ p, const float* __restrict__ hbuf,
    const float* __restrict__ bias, float* __restrict__ out)
{
  const size_t i0 = ((size_t)blockIdx.x * 256 + threadIdx.x) * 8;
  usx8 a = *(const usx8*)(p + i0);
  usx8 c = *(const usx8*)(p + 4194304 + i0);
  const int col = (int)(i0 & 1023);
  floatx4 bv0 = *(const floatx4*)(bias + col);
  floatx4 bv1 = *(const floatx4*)(bias + col + 4);
  floatx4 h0 = *(const floatx4*)(hbuf + i0);
  floatx4 h1 = *(const floatx4*)(hbuf + i0 + 4);
  floatx4 o0, o1;
  #pragma unroll
  for (int i = 0; i < 4; ++i) o0[i] = h0[i] + b2f(a[i])   + b2f(c[i])   + bv0[i];
  #pragma unroll
  for (int i = 0; i < 4; ++i) o1[i] = h1[i] + b2f(a[4+i]) + b2f(c[4+i]) + bv1[i];
  *(floatx4*)(out + i0)     = o0;
  *(floatx4*)(out + i0 + 4) = o1;
}

// ---------- launch ----------
extern "C" void kernel_launch(void* const* d_in, const int* in_sizes, int n_in,
                              void* d_out, int out_size, void* d_ws, size_t ws_size,
                              hipStream_t stream) {
  const float* hidden    = (const float*)d_in[0];
  const float* w_attn    = (const float*)d_in[1];
  const float* b_attn    = (const float*)d_in[2];
  const float* w_proj    = (const float*)d_in[3];
  const float* b_proj    = (const float*)d_in[4];
  const float* w_fc      = (const float*)d_in[5];
  const float* b_fc      = (const float*)d_in[6];
  const float* w_fc_proj = (const float*)d_in[7];
  const float* b_fc_proj = (const float*)d_in[8];
  const float* ln1_w     = (const float*)d_in[9];
  const float* ln1_b     = (const float*)d_in[10];
  const float* ln2_w     = (const float*)d_in[11];
  const float* ln2_b     = (const float*)d_in[12];

  char* wsb = (char*)d_ws;
  u16*   xb    = (u16*)  (wsb + (size_t)( 0u << 20));  //  8 MB [4096,1024]
  u16*   qkvb  = (u16*)  (wsb + (size_t)( 8u << 20));  // 24 MB [4096,3072]
  u16*   attnb = (u16*)  (wsb + (size_t)(32u << 20));  //  8 MB [4096,1024]
  float* hbuf  = (float*)(wsb + (size_t)(40u << 20));  // 16 MB [4096,1024] fp32
  u16*   opart = (u16*)  (wsb + (size_t)(40u << 20));  // 16 MB attn partials (pre-hbuf)
  float* mlbuf = (float*)(wsb + (size_t)(56u << 20));  //  2 MB attn (m,l) (over dead wqT)
  u16*   wqT   = (u16*)  (wsb + (size_t)(56u << 20));  //  6 MB [3072,1024]
  u16*   wpT   = (u16*)  (wsb + (size_t)(62u << 20));  //  2 MB [1024,1024]
  u16*   wfT   = (u16*)  (wsb + (size_t)(64u << 20));  //  8 MB [4096,1024]
  u16*   wfpT  = (u16*)  (wsb + (size_t)(72u << 20));  //  8 MB [1024,4096]
  u16*   pfcp  = (u16*)  (wsb + (size_t)(56u << 20));  // 16 MB fc_proj partials (dead wq/wp/wf)
  u16*   fcb   = qkvb;   // 32 MB [4096,4096], reuses qkvb+attnb (dead)
  u16*   yb    = xb;     // reuses xb (dead after qkv GEMM)

  // 0) weight transpose+convert fp32[K,N] -> bf16[N,K]
  wtrans_kernel<<<dim3(96, 32),  256, 0, stream>>>(w_attn,    wqT,  1024, 3072);
  wtrans_kernel<<<dim3(32, 32),  256, 0, stream>>>(w_proj,    wpT,  1024, 1024);
  wtrans_kernel<<<dim3(128, 32), 256, 0, stream>>>(w_fc,      wfT,  1024, 4096);
  wtrans_kernel<<<dim3(32, 128), 256, 0, stream>>>(w_fc_proj, wfpT, 4096, 1024);

  // 1) x = LN1(hidden) -> bf16
  ln_bf16_kernel<<<4096, 256, 0, stream>>>(hidden, ln1_w, ln1_b, xb);
  // 2) qkv = x @ w_attn + b_attn -> bf16 [4096,3072]  (wqT dead after this)
  gemm_mfma_kernel<128,128,4,4><<<dim3(24, 32, 1), 256, 0, stream>>>(
      xb, wqT, b_attn, nullptr, qkvb, 4096, 3072, 1024, 1024);
  // 3) flash attention partials (paired q-tiles, K-split x2)
  attn_mfma_kernel<<<dim3(32, 16, 2), 256, 0, stream>>>(qkvb, opart, mlbuf);
  attn_combine_kernel<<<dim3(512, 16, 2), 256, 0, stream>>>(opart, mlbuf, attnb);
  // 4) h = hidden + attn @ w_proj + b_proj -> fp32 (overwrites opart region)
  gemm_mfma_kernel<128,64,2,4><<<dim3(16, 32, 1), 256, 0, stream>>>(
      attnb, wpT, b_proj, hidden, hbuf, 4096, 1024, 1024, 1024);
  // 5) y = LN2(h) -> bf16
  ln_bf16_kernel<<<4096, 256, 0, stream>>>(hbuf, ln2_w, ln2_b, yb);
  // 6) fc = gelu(y @ w_fc + b_fc) -> bf16 [4096,4096], 256x128 tiles
  gemm_mfma_kernel<256,128,5,2><<<dim3(32, 16, 1), 256, 0, stream>>>(
      yb, wfT, b_fc, nullptr, fcb, 4096, 4096, 1024, 1024);
  // 7) fc_proj partials: K-split x2 -> bf16 p0/p1 (over dead weight regions)
  gemm_mfma_kernel<128,64,4,4><<<dim3(16, 32, 2), 256, 0, stream>>>(
      fcb, wfpT, nullptr, nullptr, pfcp, 4096, 1024, 4096, 2048);
  // 8) out = h + p0 + p1 + b_fc_proj -> fp32
  fcproj_combine_kernel<<<dim3(2048), 256, 0, stream>>>(pfcp, hbuf, b_fc_proj, (float*)d_out);
}

// Round 5
// 386.655 us; speedup vs baseline: 3.8215x; 1.0492x over previous
//
#include <hip/hip_runtime.h>
#include <cstdint>
#include <cstddef>

// ---------- types ----------
typedef unsigned short u16;
typedef float  floatx4 __attribute__((ext_vector_type(4)));
typedef short  short8  __attribute__((ext_vector_type(8)));
typedef u16    usx4    __attribute__((ext_vector_type(4)));
typedef u16    usx8    __attribute__((ext_vector_type(8)));

// fp32 -> bf16, round-to-nearest-even
__device__ __forceinline__ u16 f2b(float f) {
  unsigned u = __float_as_uint(f);
  unsigned r = u + 0x7fffu + ((u >> 16) & 1u);
  return (u16)(r >> 16);
}
__device__ __forceinline__ float b2f(u16 s) {
  return __uint_as_float(((unsigned)s) << 16);
}

__device__ __forceinline__ float gelu_f(float x) {
  const float c = 0.7978845608028654f; // sqrt(2/pi)
  float t = tanhf(c * (x + 0.044715f * x * x * x));
  return 0.5f * x * (1.0f + t);
}

// async global->LDS 16B: lds dst = wave-uniform base + lane*16 (HW rule)
__device__ __forceinline__ void gl2lds16(const u16* g, u16* l) {
  __builtin_amdgcn_global_load_lds(
      (const __attribute__((address_space(1))) unsigned int*)g,
      (__attribute__((address_space(3))) unsigned int*)l, 16, 0, 0);
}

#define C2SCALE 0.18033688011112042f  // (1/8) * log2(e)

// ---------- LayerNorm: one block per row of 1024, bf16 out ----------
__global__ __launch_bounds__(256) void ln_bf16_kernel(
    const float* __restrict__ in, const float* __restrict__ w,
    const float* __restrict__ b, u16* __restrict__ out)
{
  const int row = blockIdx.x;
  const int t = threadIdx.x;
  const float* p = in + (size_t)row * 1024 + t * 4;
  floatx4 v = *(const floatx4*)p;
  float s  = v.x + v.y + v.z + v.w;
  float ss = v.x*v.x + v.y*v.y + v.z*v.z + v.w*v.w;
  #pragma unroll
  for (int m = 1; m < 64; m <<= 1) {
    s  += __shfl_xor(s,  m);
    ss += __shfl_xor(ss, m);
  }
  __shared__ float red[8];
  if ((t & 63) == 0) { red[(t >> 6)*2] = s; red[(t >> 6)*2 + 1] = ss; }
  __syncthreads();
  s  = red[0] + red[2] + red[4] + red[6];
  ss = red[1] + red[3] + red[5] + red[7];
  const float mean = s * (1.0f / 1024.0f);
  const float var  = ss * (1.0f / 1024.0f) - mean * mean;
  const float rstd = rsqrtf(var + 1e-6f);
  floatx4 wv = *(const floatx4*)(w + t * 4);
  floatx4 bv = *(const floatx4*)(b + t * 4);
  usx4 o = { f2b(wv.x * ((v.x - mean) * rstd) + bv.x),
             f2b(wv.y * ((v.y - mean) * rstd) + bv.y),
             f2b(wv.z * ((v.z - mean) * rstd) + bv.z),
             f2b(wv.w * ((v.w - mean) * rstd) + bv.w) };
  *(usx4*)(out + (size_t)row * 1024 + t * 4) = o;
}

// ---------- weight transpose+convert: in[K,N] fp32 -> out[N,K] bf16 ----------
__global__ __launch_bounds__(256) void wtrans_kernel(
    const float* __restrict__ in, u16* __restrict__ out, int K, int N)
{
  __shared__ u16 tile[32][33];
  const int n0 = blockIdx.x * 32, k0 = blockIdx.y * 32;
  const int tx = threadIdx.x & 31, ty = threadIdx.x >> 5;  // ty 0..7
  #pragma unroll
  for (int i = 0; i < 4; ++i)
    tile[ty + i*8][tx] = f2b(in[(size_t)(k0 + ty + i*8) * N + n0 + tx]);
  __syncthreads();
  #pragma unroll
  for (int i = 0; i < 4; ++i)
    out[(size_t)(n0 + ty + i*8) * K + k0 + tx] = tile[tx][ty + i*8];
}

// ---------- GEMM (m97 structure): C[M,N] = A[M,K] @ Bt[N,K]^T ----------
// BMxBN tile, BK=32, 256 threads, 4 waves 2x2, global_load_lds(16B) staging.
// grid.z splits K: kStart = z*kLen; partial outputs offset by z*M*N.
// FLAGS: 1 = gelu, 2 = +Res (fp32), 4 = bf16 out, 8 = scale cols<1024 by C2
template<int BM, int BN, int FLAGS, int MINW>
__global__ __launch_bounds__(256, MINW) void gemm_mfma_kernel(
    const u16* __restrict__ A, const u16* __restrict__ Bt,
    const float* __restrict__ bias, const float* __restrict__ Res,
    void* __restrict__ Cout, int M, int N, int K, int kLen)
{
  constexpr int WM = BM / 2, WN = BN / 2;
  constexpr int MT = WM / 16, NT = WN / 16;
  __shared__ u16 As[BM * 32];
  __shared__ u16 Bs[BN * 32];

  const int t = threadIdx.x;
  const int wave = t >> 6, lane = t & 63;
  const int quad = lane >> 4, l16 = lane & 15;
  const int wm = wave >> 1, wn = wave & 1;
  const int bm0 = blockIdx.y * BM, bn0 = blockIdx.x * BN;
  const int kStart = blockIdx.z * kLen;

  const int sRow = lane >> 2;
  const int sq   = lane & 3;

  const u16* aG[BM / 64];
  u16* aL[BM / 64];
  #pragma unroll
  for (int j = 0; j < BM / 64; ++j) {
    const int band = j * 4 + wave;
    aG[j] = A + (size_t)(bm0 + band * 16 + sRow) * K + kStart + sq * 8;
    aL[j] = As + band * 512;
  }
  const u16* bG[BN / 64];
  u16* bL[BN / 64];
  #pragma unroll
  for (int j = 0; j < BN / 64; ++j) {
    const int band = j * 4 + wave;
    bG[j] = Bt + (size_t)(bn0 + band * 16 + sRow) * K + kStart + sq * 8;
    bL[j] = Bs + band * 512;
  }

  floatx4 acc[MT][NT] = {};

  for (int k0 = 0; k0 < kLen; k0 += 32) {
    __syncthreads();
    #pragma unroll
    for (int j = 0; j < BM / 64; ++j) gl2lds16(aG[j] + k0, aL[j]);
    #pragma unroll
    for (int j = 0; j < BN / 64; ++j) gl2lds16(bG[j] + k0, bL[j]);
    __syncthreads();

    short8 af[MT], bf[NT];
    #pragma unroll
    for (int mt = 0; mt < MT; ++mt)
      af[mt] = *(const short8*)&As[(wm*WM + mt*16 + l16) * 32 + quad * 8];
    #pragma unroll
    for (int nt = 0; nt < NT; ++nt)
      bf[nt] = *(const short8*)&Bs[(wn*WN + nt*16 + l16) * 32 + quad * 8];
    #pragma unroll
    for (int mt = 0; mt < MT; ++mt)
      #pragma unroll
      for (int nt = 0; nt < NT; ++nt)
        acc[mt][nt] = __builtin_amdgcn_mfma_f32_16x16x32_bf16(af[mt], bf[nt], acc[mt][nt], 0, 0, 0);
  }

  // epilogue: C/D layout col=lane&15, row=quad*4+reg
  const int orow0 = bm0 + wm * WM;
  const int ocol0 = bn0 + wn * WN;
  const size_t zoff = (size_t)blockIdx.z * M * N;
  #pragma unroll
  for (int nt = 0; nt < NT; ++nt) {
    const int col = ocol0 + nt*16 + l16;
    const float bv = bias ? bias[col] : 0.0f;
    const float postscale = ((FLAGS & 8) && col < 1024) ? C2SCALE : 1.0f;
    #pragma unroll
    for (int mt = 0; mt < MT; ++mt) {
      #pragma unroll
      for (int r = 0; r < 4; ++r) {
        const int row = orow0 + mt*16 + quad*4 + r;
        float v = acc[mt][nt][r] + bv;
        if (FLAGS & 1) v = gelu_f(v);
        if (FLAGS & 8) v *= postscale;
        if (FLAGS & 2) v += Res[(size_t)row * N + col];
        if (FLAGS & 4) ((u16*)Cout)[zoff + (size_t)row * N + col] = f2b(v);
        else           ((float*)Cout)[zoff + (size_t)row * N + col] = v;
      }
    }
  }
}

// ---------- MFMA flash attention (causal), bf16, balanced + K-split ----------
// Q is PRE-SCALED by C2 = (1/8)*log2(e); softmax runs in exp2 domain.
// grid: (32, H, B): pair = x>>1 (0..15), half = x&1.
// Block: q-tiles {pair, 31-pair} (64 rows each), key partition `half`.
// Denominator l accumulated via ones-column MFMA (no shuffle reduction).
// opart: [part][b][h][2048][64] bf16 ; ml: [part][b][h][2048][2] fp32
__global__ __launch_bounds__(256, 4) void attn_mfma_kernel(
    const u16* __restrict__ qkv, u16* __restrict__ opart, float* __restrict__ ml)
{
  __shared__ u16 Ks[64][72];  // K tile [key][dh] (also Q staging)
  __shared__ u16 Vt[64][72];  // V tile transposed [dh][key]
  __shared__ u16 Ps[64][72];  // P per wave: rows [w*16, w*16+16)

  const int t    = threadIdx.x;
  const int wave = t >> 6;
  const int lane = t & 63;
  const int quad = lane >> 4;
  const int l16  = lane & 15;
  const int pair = blockIdx.x >> 1;
  const int half = blockIdx.x & 1;
  const int h    = blockIdx.y;
  const int b    = blockIdx.z;

  const size_t base = (size_t)b * 2048 * 3072;
  const int qoff = h * 64;
  const int koff = 1024 + h * 64;
  const int voff = 2048 + h * 64;

  const int srow = t >> 2;          // K/Q staging row
  const int scol = (t & 3) * 16;    // K/Q staging col chunk
  const int kpair  = t & 31;        // V staging: keys 2*kpair, 2*kpair+1
  const int vchunk = t >> 5;        // V staging: dh chunk (0..7)

  const size_t obase  = ((((size_t)half * 2 + b) * 16 + h) * 2048) * 64;
  const size_t mlbase = ((((size_t)half * 2 + b) * 16 + h) * 2048) * 2;

  // ones B-fragment: B[0][k]=1.0, B[1..15][k]=0 — row sums via MFMA
  short8 onesb;
  {
    const short v = (l16 == 0) ? (short)0x3F80 : (short)0;
    #pragma unroll
    for (int i = 0; i < 8; ++i) onesb[i] = v;
  }

  #pragma unroll 1
  for (int iter = 0; iter < 2; ++iter) {
    const int qi = iter ? (31 - pair) : pair;
    const int q0 = qi << 6;
    const int T  = qi + 1;
    const int mid = (T + 1) >> 1;
    const int t0 = half ? mid : 0;
    const int t1 = half ? T : mid;

    floatx4 of[4] = {};
    floatx4 ofl = {};           // l accumulator (col 0 lanes meaningful)
    float m[4];
    #pragma unroll
    for (int r = 0; r < 4; ++r) m[r] = -1e30f;

    if (t0 < t1) {
      // ---- stage Q into Ks, grab per-wave A-fragments ----
      __syncthreads();
      {
        const u16* qp = qkv + base + (size_t)(q0 + srow) * 3072 + qoff + scol;
        *(usx8*)&Ks[srow][scol]     = *(const usx8*)qp;
        *(usx8*)&Ks[srow][scol + 8] = *(const usx8*)(qp + 8);
      }
      __syncthreads();
      const short8 qf0 = *(const short8*)&Ks[wave*16 + l16][quad*8];
      const short8 qf1 = *(const short8*)&Ks[wave*16 + l16][32 + quad*8];

      // ---- prefetch first K/V tile into regs ----
      usx8 kr0, kr1, vr0, vr1;
      {
        const int k0 = t0 << 6;
        const u16* kp = qkv + base + (size_t)(k0 + srow) * 3072 + koff + scol;
        kr0 = *(const usx8*)kp; kr1 = *(const usx8*)(kp + 8);
        const u16* vp = qkv + base + (size_t)(k0 + 2*kpair) * 3072 + voff + vchunk*8;
        vr0 = *(const usx8*)vp; vr1 = *(const usx8*)(vp + 3072);
      }

      for (int tIdx = t0; tIdx < t1; ++tIdx) {
        __syncthreads();
        *(usx8*)&Ks[srow][scol]     = kr0;
        *(usx8*)&Ks[srow][scol + 8] = kr1;
        #pragma unroll
        for (int i = 0; i < 8; ++i)
          *(unsigned*)&Vt[vchunk*8 + i][2*kpair] =
              (unsigned)vr0[i] | ((unsigned)vr1[i] << 16);
        __syncthreads();

        if (tIdx + 1 < t1) {
          const int kn = (tIdx + 1) << 6;
          const u16* kp = qkv + base + (size_t)(kn + srow) * 3072 + koff + scol;
          kr0 = *(const usx8*)kp; kr1 = *(const usx8*)(kp + 8);
          const u16* vp = qkv + base + (size_t)(kn + 2*kpair) * 3072 + voff + vchunk*8;
          vr0 = *(const usx8*)vp; vr1 = *(const usx8*)(vp + 3072);
        }

        // ---- S = Q K^T (already in log2 domain; Q pre-scaled) ----
        const int k0 = tIdx << 6;
        floatx4 sf[4];
        #pragma unroll
        for (int kt = 0; kt < 4; ++kt) {
          short8 kf0 = *(const short8*)&Ks[kt*16 + l16][quad*8];
          short8 kf1 = *(const short8*)&Ks[kt*16 + l16][32 + quad*8];
          floatx4 z = {};
          z      = __builtin_amdgcn_mfma_f32_16x16x32_bf16(qf0, kf0, z, 0, 0, 0);
          sf[kt] = __builtin_amdgcn_mfma_f32_16x16x32_bf16(qf1, kf1, z, 0, 0, 0);
        }

        // ---- online softmax (no sum reduction; l via ones-MFMA) ----
        const bool diag = (tIdx == qi);
        #pragma unroll
        for (int r = 0; r < 4; ++r) {
          float sv0 = sf[0][r], sv1 = sf[1][r], sv2 = sf[2][r], sv3 = sf[3][r];
          if (diag) {
            const int qrow = q0 + wave*16 + quad*4 + r;
            if (k0 +      l16 > qrow) sv0 = -1e30f;
            if (k0 + 16 + l16 > qrow) sv1 = -1e30f;
            if (k0 + 32 + l16 > qrow) sv2 = -1e30f;
            if (k0 + 48 + l16 > qrow) sv3 = -1e30f;
          }
          float mx = fmaxf(fmaxf(sv0, sv1), fmaxf(sv2, sv3));
          #pragma unroll
          for (int msk = 1; msk < 16; msk <<= 1) mx = fmaxf(mx, __shfl_xor(mx, msk, 16));
          const float nm = fmaxf(m[r], mx);
          const float alpha = exp2f(m[r] - nm);
          m[r] = nm;
          Ps[wave*16 + quad*4 + r][     l16] = f2b(exp2f(sv0 - nm));
          Ps[wave*16 + quad*4 + r][16 + l16] = f2b(exp2f(sv1 - nm));
          Ps[wave*16 + quad*4 + r][32 + l16] = f2b(exp2f(sv2 - nm));
          Ps[wave*16 + quad*4 + r][48 + l16] = f2b(exp2f(sv3 - nm));
          #pragma unroll
          for (int dht = 0; dht < 4; ++dht) of[dht][r] *= alpha;
          ofl[r] *= alpha;
        }

        // ---- O += P V ; l += P 1 ----
        short8 pf0 = *(const short8*)&Ps[wave*16 + l16][quad*8];
        short8 pf1 = *(const short8*)&Ps[wave*16 + l16][32 + quad*8];
        #pragma unroll
        for (int dht = 0; dht < 4; ++dht) {
          short8 vf0 = *(const short8*)&Vt[dht*16 + l16][quad*8];
          short8 vf1 = *(const short8*)&Vt[dht*16 + l16][32 + quad*8];
          of[dht] = __builtin_amdgcn_mfma_f32_16x16x32_bf16(pf0, vf0, of[dht], 0, 0, 0);
          of[dht] = __builtin_amdgcn_mfma_f32_16x16x32_bf16(pf1, vf1, of[dht], 0, 0, 0);
        }
        ofl = __builtin_amdgcn_mfma_f32_16x16x32_bf16(pf0, onesb, ofl, 0, 0, 0);
        ofl = __builtin_amdgcn_mfma_f32_16x16x32_bf16(pf1, onesb, ofl, 0, 0, 0);
      }
    }

    // ---- write partial (unnormalized O + m,l) ----
    #pragma unroll
    for (int r = 0; r < 4; ++r) {
      const int s = q0 + wave*16 + quad*4 + r;
      u16* orow = opart + obase + (size_t)s * 64;
      #pragma unroll
      for (int dht = 0; dht < 4; ++dht) orow[dht*16 + l16] = f2b(of[dht][r]);
      const float lr = __shfl(ofl[r], quad * 16);   // col 0 of this row block
      if (l16 == 0) { ml[mlbase + 2*s] = m[r]; ml[mlbase + 2*s + 1] = lr; }
    }
  }
}

// ---------- combine attention partials -> attnb bf16 [B,S,1024] ----------
__global__ __launch_bounds__(256) void attn_combine_kernel(
    const u16* __restrict__ opart, const float* __restrict__ ml,
    u16* __restrict__ out)
{
  const int t = threadIdx.x;
  const int s = blockIdx.x * 4 + (t >> 6);
  const int lane = t & 63;
  const int h = blockIdx.y, b = blockIdx.z;

  const size_t o0  = ((((size_t)0 * 2 + b) * 16 + h) * 2048 + s) * 64 + lane;
  const size_t o1  = ((((size_t)1 * 2 + b) * 16 + h) * 2048 + s) * 64 + lane;
  const size_t ml0 = ((((size_t)0 * 2 + b) * 16 + h) * 2048 + s) * 2;
  const size_t ml1 = ((((size_t)1 * 2 + b) * 16 + h) * 2048 + s) * 2;

  const float m0 = ml[ml0], l0 = ml[ml0 + 1];
  const float m1 = ml[ml1], l1 = ml[ml1 + 1];
  const float M  = fmaxf(m0, m1);
  const float w0 = exp2f(m0 - M), w1 = exp2f(m1 - M);
  const float L  = w0 * l0 + w1 * l1;
  const float o  = w0 * b2f(opart[o0]) + w1 * b2f(opart[o1]);
  out[((size_t)b * 2048 + s) * 1024 + h * 64 + lane] = f2b(o / L);
}

// ---------- fc_proj K-split combine: out = res + p0 + p1 + bias ----------
__global__ __launch_bounds__(256) void fcproj_combine_kernel(
    const u16* __restrict__ p, const float* __restrict__ res,
    const float* __restrict__ bias, float* __restrict__ out)
{
  const size_t i0 = ((size_t)blockIdx.x * 256 + threadIdx.x) * 8;
  usx8 a = *(const usx8*)(p + i0);
  usx8 c = *(const usx8*)(p + 4194304 + i0);
  const int col = (int)(i0 & 1023);
  floatx4 bv0 = *(const floatx4*)(bias + col);
  floatx4 bv1 = *(const floatx4*)(bias + col + 4);
  floatx4 h0 = *(const floatx4*)(res + i0);
  floatx4 h1 = *(const floatx4*)(res + i0 + 4);
  floatx4 o0, o1;
  #pragma unroll
  for (int i = 0; i < 4; ++i) o0[i] = h0[i] + b2f(a[i])   + b2f(c[i])   + bv0[i];
  #pragma unroll
  for (int i = 0; i < 4; ++i) o1[i] = h1[i] + b2f(a[4+i]) + b2f(c[4+i]) + bv1[i];
  *(floatx4*)(out + i0)     = o0;
  *(floatx4*)(out + i0 + 4) = o1;
}

// ---------- launch ----------
extern "C" void kernel_launch(void* const* d_in, const int* in_sizes, int n_in,
                              void* d_out, int out_size, void* d_ws, size_t ws_size,
                              hipStream_t stream) {
  const float* hidden    = (const float*)d_in[0];
  const float* w_attn    = (const float*)d_in[1];
  const float* b_attn    = (const float*)d_in[2];
  const float* w_proj    = (const float*)d_in[3];
  const float* b_proj    = (const float*)d_in[4];
  const float* w_fc      = (const float*)d_in[5];
  const float* b_fc      = (const float*)d_in[6];
  const float* w_fc_proj = (const float*)d_in[7];
  const float* b_fc_proj = (const float*)d_in[8];
  const float* ln1_w     = (const float*)d_in[9];
  const float* ln1_b     = (const float*)d_in[10];
  const float* ln2_w     = (const float*)d_in[11];
  const float* ln2_b     = (const float*)d_in[12];

  char* wsb = (char*)d_ws;
  u16*   xb    = (u16*)  (wsb + (size_t)( 0u << 20));  //  8 MB [4096,1024]
  u16*   qkvb  = (u16*)  (wsb + (size_t)( 8u << 20));  // 24 MB [4096,3072]
  u16*   attnb = (u16*)  (wsb + (size_t)(32u << 20));  //  8 MB [4096,1024]
  float* hbuf  = (float*)(wsb + (size_t)(40u << 20));  // 16 MB [4096,1024] fp32
  u16*   opart = (u16*)  (wsb + (size_t)(40u << 20));  // 16 MB attn partials (pre-hbuf)
  float* mlbuf = (float*)(wsb + (size_t)(56u << 20));  //  2 MB attn (m,l) (over dead wqT)
  u16*   wqT   = (u16*)  (wsb + (size_t)(56u << 20));  //  6 MB [3072,1024]
  u16*   wpT   = (u16*)  (wsb + (size_t)(62u << 20));  //  2 MB [1024,1024]
  u16*   wfT   = (u16*)  (wsb + (size_t)(64u << 20));  //  8 MB [4096,1024]
  u16*   wfpT  = (u16*)  (wsb + (size_t)(72u << 20));  //  8 MB [1024,4096]
  u16*   pfcp  = (u16*)  (wsb + (size_t)(56u << 20));  // 16 MB fc_proj partials (dead wq/wp/wf)
  u16*   fcb   = qkvb;   // 32 MB [4096,4096], reuses qkvb+attnb (dead)
  u16*   yb    = xb;     // reuses xb (dead after qkv GEMM)

  // 0) weight transpose+convert fp32[K,N] -> bf16[N,K]
  wtrans_kernel<<<dim3(96, 32),  256, 0, stream>>>(w_attn,    wqT,  1024, 3072);
  wtrans_kernel<<<dim3(32, 32),  256, 0, stream>>>(w_proj,    wpT,  1024, 1024);
  wtrans_kernel<<<dim3(128, 32), 256, 0, stream>>>(w_fc,      wfT,  1024, 4096);
  wtrans_kernel<<<dim3(32, 128), 256, 0, stream>>>(w_fc_proj, wfpT, 4096, 1024);

  // 1) x = LN1(hidden) -> bf16
  ln_bf16_kernel<<<4096, 256, 0, stream>>>(hidden, ln1_w, ln1_b, xb);
  // 2) qkv = x @ w_attn + b_attn -> bf16; q-cols pre-scaled by C2 (flag 8)
  gemm_mfma_kernel<128,128,12,4><<<dim3(24, 32, 1), 256, 0, stream>>>(
      xb, wqT, b_attn, nullptr, qkvb, 4096, 3072, 1024, 1024);
  // 3) flash attention partials (paired q-tiles, K-split x2)
  attn_mfma_kernel<<<dim3(32, 16, 2), 256, 0, stream>>>(qkvb, opart, mlbuf);
  attn_combine_kernel<<<dim3(512, 16, 2), 256, 0, stream>>>(opart, mlbuf, attnb);
  // 4) h = hidden + attn @ w_proj + b_proj -> fp32 (overwrites opart region)
  gemm_mfma_kernel<128,64,2,4><<<dim3(16, 32, 1), 256, 0, stream>>>(
      attnb, wpT, b_proj, hidden, hbuf, 4096, 1024, 1024, 1024);
  // 5) y = LN2(h) -> bf16
  ln_bf16_kernel<<<4096, 256, 0, stream>>>(hbuf, ln2_w, ln2_b, yb);
  // 6) fc = gelu(y @ w_fc + b_fc) -> bf16 [4096,4096], 256x128 tiles
  gemm_mfma_kernel<256,128,5,2><<<dim3(32, 16, 1), 256, 0, stream>>>(
      yb, wfT, b_fc, nullptr, fcb, 4096, 4096, 1024, 1024);
  // 7) fc_proj partials: K-split x2, 128x128 tiles -> bf16 p0/p1
  gemm_mfma_kernel<128,128,4,4><<<dim3(8, 32, 2), 256, 0, stream>>>(
      fcb, wfpT, nullptr, nullptr, pfcp, 4096, 1024, 4096, 2048);
  // 8) out = h + p0 + p1 + b_fc_proj -> fp32
  fcproj_combine_kernel<<<dim3(2048), 256, 0, stream>>>(pfcp, hbuf, b_fc_proj, (float*)d_out);
}

// Round 6
// 382.242 us; speedup vs baseline: 3.8656x; 1.0115x over previous
//
#include <hip/hip_runtime.h>
#include <cstdint>
#include <cstddef>

// ---------- types ----------
typedef unsigned short u16;
typedef float  floatx4 __attribute__((ext_vector_type(4)));
typedef short  short8  __attribute__((ext_vector_type(8)));
typedef u16    usx4    __attribute__((ext_vector_type(4)));
typedef u16    usx8    __attribute__((ext_vector_type(8)));

// fp32 -> bf16, round-to-nearest-even
__device__ __forceinline__ u16 f2b(float f) {
  unsigned u = __float_as_uint(f);
  unsigned r = u + 0x7fffu + ((u >> 16) & 1u);
  return (u16)(r >> 16);
}
__device__ __forceinline__ float b2f(u16 s) {
  return __uint_as_float(((unsigned)s) << 16);
}

// GPT-2 tanh-gelu, exact algebraic rewrite: 0.5x(1+tanh(u)) = x*sigmoid(2u)
// sigmoid via native exp2 + rcp (bf16-output accuracy is unaffected).
__device__ __forceinline__ float gelu_f(float x) {
  const float k = 2.3022082f;  // 2*sqrt(2/pi)*log2(e)
  float u = x * (1.0f + 0.044715f * x * x);
  float t = __builtin_amdgcn_exp2f(-k * u);
  return x * __builtin_amdgcn_rcpf(1.0f + t);
}

// async global->LDS 16B: lds dst = wave-uniform base + lane*16 (HW rule);
// global source address may be per-lane.
__device__ __forceinline__ void gl2lds16(const u16* g, u16* l) {
  __builtin_amdgcn_global_load_lds(
      (const __attribute__((address_space(1))) unsigned int*)g,
      (__attribute__((address_space(3))) unsigned int*)l, 16, 0, 0);
}

#define C2SCALE 0.18033688011112042f  // (1/8) * log2(e)

// ---------- LayerNorm: one block per row of 1024, bf16 out ----------
__global__ __launch_bounds__(256) void ln_bf16_kernel(
    const float* __restrict__ in, const float* __restrict__ w,
    const float* __restrict__ b, u16* __restrict__ out)
{
  const int row = blockIdx.x;
  const int t = threadIdx.x;
  const float* p = in + (size_t)row * 1024 + t * 4;
  floatx4 v = *(const floatx4*)p;
  float s  = v.x + v.y + v.z + v.w;
  float ss = v.x*v.x + v.y*v.y + v.z*v.z + v.w*v.w;
  #pragma unroll
  for (int m = 1; m < 64; m <<= 1) {
    s  += __shfl_xor(s,  m);
    ss += __shfl_xor(ss, m);
  }
  __shared__ float red[8];
  if ((t & 63) == 0) { red[(t >> 6)*2] = s; red[(t >> 6)*2 + 1] = ss; }
  __syncthreads();
  s  = red[0] + red[2] + red[4] + red[6];
  ss = red[1] + red[3] + red[5] + red[7];
  const float mean = s * (1.0f / 1024.0f);
  const float var  = ss * (1.0f / 1024.0f) - mean * mean;
  const float rstd = rsqrtf(var + 1e-6f);
  floatx4 wv = *(const floatx4*)(w + t * 4);
  floatx4 bv = *(const floatx4*)(b + t * 4);
  usx4 o = { f2b(wv.x * ((v.x - mean) * rstd) + bv.x),
             f2b(wv.y * ((v.y - mean) * rstd) + bv.y),
             f2b(wv.z * ((v.z - mean) * rstd) + bv.z),
             f2b(wv.w * ((v.w - mean) * rstd) + bv.w) };
  *(usx4*)(out + (size_t)row * 1024 + t * 4) = o;
}

// ---------- weight transpose+convert: in[K,N] fp32 -> out[N,K] bf16 ----------
__global__ __launch_bounds__(256) void wtrans_kernel(
    const float* __restrict__ in, u16* __restrict__ out, int K, int N)
{
  __shared__ u16 tile[32][33];
  const int n0 = blockIdx.x * 32, k0 = blockIdx.y * 32;
  const int tx = threadIdx.x & 31, ty = threadIdx.x >> 5;  // ty 0..7
  #pragma unroll
  for (int i = 0; i < 4; ++i)
    tile[ty + i*8][tx] = f2b(in[(size_t)(k0 + ty + i*8) * N + n0 + tx]);
  __syncthreads();
  #pragma unroll
  for (int i = 0; i < 4; ++i)
    out[(size_t)(n0 + ty + i*8) * K + k0 + tx] = tile[tx][ty + i*8];
}

// ---------- GEMM (m97 structure): C[M,N] = A[M,K] @ Bt[N,K]^T ----------
// BMxBN tile, BK=32, 256 threads, 4 waves 2x2, global_load_lds(16B) staging.
// XOR chunk swizzle (on the DMA *source*) makes frag reads 4-way instead of
// 8-way bank-conflicted. grid.z splits K: kStart = z*kLen; partial z-outputs
// at Cout + z*zStride (elements).
// FLAGS: 1 = gelu, 2 = +Res (fp32), 4 = bf16 out, 8 = scale cols<1024 by C2
template<int BM, int BN, int FLAGS, int MINW>
__global__ __launch_bounds__(256, MINW) void gemm_mfma_kernel(
    const u16* __restrict__ A, const u16* __restrict__ Bt,
    const float* __restrict__ bias, const float* __restrict__ Res,
    void* __restrict__ Cout, int M, int N, int K, int kLen, size_t zStride)
{
  constexpr int WM = BM / 2, WN = BN / 2;
  constexpr int MT = WM / 16, NT = WN / 16;
  __shared__ u16 As[BM * 32];
  __shared__ u16 Bs[BN * 32];

  const int t = threadIdx.x;
  const int wave = t >> 6, lane = t & 63;
  const int quad = lane >> 4, l16 = lane & 15;
  const int wm = wave >> 1, wn = wave & 1;
  const int bm0 = blockIdx.y * BM, bn0 = blockIdx.x * BN;
  const int kStart = blockIdx.z * kLen;

  // staging: one issue = 16 rows x 64B. lane -> row lane>>2; fetch the XOR-
  // swizzled global 16B chunk so LDS[r][c] = G[r][c ^ (r&3)].
  const int sRow = lane >> 2;
  const int sq   = (lane & 3) ^ (sRow & 3);

  const u16* aG[BM / 64];
  u16* aL[BM / 64];
  #pragma unroll
  for (int j = 0; j < BM / 64; ++j) {
    const int band = j * 4 + wave;
    aG[j] = A + (size_t)(bm0 + band * 16 + sRow) * K + kStart + sq * 8;
    aL[j] = As + band * 512;
  }
  const u16* bG[BN / 64];
  u16* bL[BN / 64];
  #pragma unroll
  for (int j = 0; j < BN / 64; ++j) {
    const int band = j * 4 + wave;
    bG[j] = Bt + (size_t)(bn0 + band * 16 + sRow) * K + kStart + sq * 8;
    bL[j] = Bs + band * 512;
  }

  floatx4 acc[MT][NT] = {};
  const int rcol = (quad ^ (l16 & 3)) << 3;   // read col: G chunk `quad`

  for (int k0 = 0; k0 < kLen; k0 += 32) {
    __syncthreads();
    #pragma unroll
    for (int j = 0; j < BM / 64; ++j) gl2lds16(aG[j] + k0, aL[j]);
    #pragma unroll
    for (int j = 0; j < BN / 64; ++j) gl2lds16(bG[j] + k0, bL[j]);
    __syncthreads();

    short8 af[MT], bf[NT];
    #pragma unroll
    for (int mt = 0; mt < MT; ++mt)
      af[mt] = *(const short8*)&As[(wm*WM + mt*16 + l16) * 32 + rcol];
    #pragma unroll
    for (int nt = 0; nt < NT; ++nt)
      bf[nt] = *(const short8*)&Bs[(wn*WN + nt*16 + l16) * 32 + rcol];
    #pragma unroll
    for (int mt = 0; mt < MT; ++mt)
      #pragma unroll
      for (int nt = 0; nt < NT; ++nt)
        acc[mt][nt] = __builtin_amdgcn_mfma_f32_16x16x32_bf16(af[mt], bf[nt], acc[mt][nt], 0, 0, 0);
  }

  // epilogue: C/D layout col=lane&15, row=quad*4+reg
  const int orow0 = bm0 + wm * WM;
  const int ocol0 = bn0 + wn * WN;
  const size_t zoff = (size_t)blockIdx.z * zStride;
  #pragma unroll
  for (int nt = 0; nt < NT; ++nt) {
    const int col = ocol0 + nt*16 + l16;
    const float bv = bias ? bias[col] : 0.0f;
    const float postscale = ((FLAGS & 8) && col < 1024) ? C2SCALE : 1.0f;
    #pragma unroll
    for (int mt = 0; mt < MT; ++mt) {
      #pragma unroll
      for (int r = 0; r < 4; ++r) {
        const int row = orow0 + mt*16 + quad*4 + r;
        float v = acc[mt][nt][r] + bv;
        if (FLAGS & 1) v = gelu_f(v);
        if (FLAGS & 8) v *= postscale;
        if (FLAGS & 2) v += Res[(size_t)row * N + col];
        if (FLAGS & 4) ((u16*)Cout)[zoff + (size_t)row * N + col] = f2b(v);
        else           ((float*)Cout)[zoff + (size_t)row * N + col] = v;
      }
    }
  }
}

// ---------- MFMA flash attention (causal), bf16, balanced + K-split ----------
// Q is PRE-SCALED by C2 = (1/8)*log2(e); softmax runs in exp2 domain.
// grid: (32, H, B): pair = x>>1 (0..15), half = x&1.
// Block: q-tiles {pair, 31-pair} (64 rows each), key partition `half`.
// Denominator l accumulated via ones-column MFMA (no shuffle reduction).
// opart: [part][b][h][2048][64] bf16 ; ml: [part][b][h][2048][2] fp32
__global__ __launch_bounds__(256, 4) void attn_mfma_kernel(
    const u16* __restrict__ qkv, u16* __restrict__ opart, float* __restrict__ ml)
{
  __shared__ u16 Ks[64][72];  // K tile [key][dh] (also Q staging)
  __shared__ u16 Vt[64][72];  // V tile transposed [dh][key]
  __shared__ u16 Ps[64][72];  // P per wave: rows [w*16, w*16+16)

  const int t    = threadIdx.x;
  const int wave = t >> 6;
  const int lane = t & 63;
  const int quad = lane >> 4;
  const int l16  = lane & 15;
  const int pair = blockIdx.x >> 1;
  const int half = blockIdx.x & 1;
  const int h    = blockIdx.y;
  const int b    = blockIdx.z;

  const size_t base = (size_t)b * 2048 * 3072;
  const int qoff = h * 64;
  const int koff = 1024 + h * 64;
  const int voff = 2048 + h * 64;

  const int srow = t >> 2;          // K/Q staging row
  const int scol = (t & 3) * 16;    // K/Q staging col chunk
  const int kpair  = t & 31;        // V staging: keys 2*kpair, 2*kpair+1
  const int vchunk = t >> 5;        // V staging: dh chunk (0..7)

  const size_t obase  = ((((size_t)half * 2 + b) * 16 + h) * 2048) * 64;
  const size_t mlbase = ((((size_t)half * 2 + b) * 16 + h) * 2048) * 2;

  // ones B-fragment: B[0][k]=1.0, B[1..15][k]=0 — row sums via MFMA
  short8 onesb;
  {
    const short v = (l16 == 0) ? (short)0x3F80 : (short)0;
    #pragma unroll
    for (int i = 0; i < 8; ++i) onesb[i] = v;
  }

  #pragma unroll 1
  for (int iter = 0; iter < 2; ++iter) {
    const int qi = iter ? (31 - pair) : pair;
    const int q0 = qi << 6;
    const int T  = qi + 1;
    const int mid = (T + 1) >> 1;
    const int t0 = half ? mid : 0;
    const int t1 = half ? T : mid;

    floatx4 of[4] = {};
    floatx4 ofl = {};           // l accumulator (col 0 lanes meaningful)
    float m[4];
    #pragma unroll
    for (int r = 0; r < 4; ++r) m[r] = -1e30f;

    if (t0 < t1) {
      // ---- stage Q into Ks, grab per-wave A-fragments ----
      __syncthreads();
      {
        const u16* qp = qkv + base + (size_t)(q0 + srow) * 3072 + qoff + scol;
        *(usx8*)&Ks[srow][scol]     = *(const usx8*)qp;
        *(usx8*)&Ks[srow][scol + 8] = *(const usx8*)(qp + 8);
      }
      __syncthreads();
      const short8 qf0 = *(const short8*)&Ks[wave*16 + l16][quad*8];
      const short8 qf1 = *(const short8*)&Ks[wave*16 + l16][32 + quad*8];

      // ---- prefetch first K/V tile into regs ----
      usx8 kr0, kr1, vr0, vr1;
      {
        const int k0 = t0 << 6;
        const u16* kp = qkv + base + (size_t)(k0 + srow) * 3072 + koff + scol;
        kr0 = *(const usx8*)kp; kr1 = *(const usx8*)(kp + 8);
        const u16* vp = qkv + base + (size_t)(k0 + 2*kpair) * 3072 + voff + vchunk*8;
        vr0 = *(const usx8*)vp; vr1 = *(const usx8*)(vp + 3072);
      }

      for (int tIdx = t0; tIdx < t1; ++tIdx) {
        __syncthreads();
        *(usx8*)&Ks[srow][scol]     = kr0;
        *(usx8*)&Ks[srow][scol + 8] = kr1;
        #pragma unroll
        for (int i = 0; i < 8; ++i)
          *(unsigned*)&Vt[vchunk*8 + i][2*kpair] =
              (unsigned)vr0[i] | ((unsigned)vr1[i] << 16);
        __syncthreads();

        if (tIdx + 1 < t1) {
          const int kn = (tIdx + 1) << 6;
          const u16* kp = qkv + base + (size_t)(kn + srow) * 3072 + koff + scol;
          kr0 = *(const usx8*)kp; kr1 = *(const usx8*)(kp + 8);
          const u16* vp = qkv + base + (size_t)(kn + 2*kpair) * 3072 + voff + vchunk*8;
          vr0 = *(const usx8*)vp; vr1 = *(const usx8*)(vp + 3072);
        }

        // ---- S = Q K^T (already in log2 domain; Q pre-scaled) ----
        const int k0 = tIdx << 6;
        floatx4 sf[4];
        #pragma unroll
        for (int kt = 0; kt < 4; ++kt) {
          short8 kf0 = *(const short8*)&Ks[kt*16 + l16][quad*8];
          short8 kf1 = *(const short8*)&Ks[kt*16 + l16][32 + quad*8];
          floatx4 z = {};
          z      = __builtin_amdgcn_mfma_f32_16x16x32_bf16(qf0, kf0, z, 0, 0, 0);
          sf[kt] = __builtin_amdgcn_mfma_f32_16x16x32_bf16(qf1, kf1, z, 0, 0, 0);
        }

        // ---- online softmax (no sum reduction; l via ones-MFMA) ----
        const bool diag = (tIdx == qi);
        #pragma unroll
        for (int r = 0; r < 4; ++r) {
          float sv0 = sf[0][r], sv1 = sf[1][r], sv2 = sf[2][r], sv3 = sf[3][r];
          if (diag) {
            const int qrow = q0 + wave*16 + quad*4 + r;
            if (k0 +      l16 > qrow) sv0 = -1e30f;
            if (k0 + 16 + l16 > qrow) sv1 = -1e30f;
            if (k0 + 32 + l16 > qrow) sv2 = -1e30f;
            if (k0 + 48 + l16 > qrow) sv3 = -1e30f;
          }
          float mx = fmaxf(fmaxf(sv0, sv1), fmaxf(sv2, sv3));
          #pragma unroll
          for (int msk = 1; msk < 16; msk <<= 1) mx = fmaxf(mx, __shfl_xor(mx, msk, 16));
          const float nm = fmaxf(m[r], mx);
          const float alpha = exp2f(m[r] - nm);
          m[r] = nm;
          Ps[wave*16 + quad*4 + r][     l16] = f2b(exp2f(sv0 - nm));
          Ps[wave*16 + quad*4 + r][16 + l16] = f2b(exp2f(sv1 - nm));
          Ps[wave*16 + quad*4 + r][32 + l16] = f2b(exp2f(sv2 - nm));
          Ps[wave*16 + quad*4 + r][48 + l16] = f2b(exp2f(sv3 - nm));
          #pragma unroll
          for (int dht = 0; dht < 4; ++dht) of[dht][r] *= alpha;
          ofl[r] *= alpha;
        }

        // ---- O += P V ; l += P 1 ----
        short8 pf0 = *(const short8*)&Ps[wave*16 + l16][quad*8];
        short8 pf1 = *(const short8*)&Ps[wave*16 + l16][32 + quad*8];
        #pragma unroll
        for (int dht = 0; dht < 4; ++dht) {
          short8 vf0 = *(const short8*)&Vt[dht*16 + l16][quad*8];
          short8 vf1 = *(const short8*)&Vt[dht*16 + l16][32 + quad*8];
          of[dht] = __builtin_amdgcn_mfma_f32_16x16x32_bf16(pf0, vf0, of[dht], 0, 0, 0);
          of[dht] = __builtin_amdgcn_mfma_f32_16x16x32_bf16(pf1, vf1, of[dht], 0, 0, 0);
        }
        ofl = __builtin_amdgcn_mfma_f32_16x16x32_bf16(pf0, onesb, ofl, 0, 0, 0);
        ofl = __builtin_amdgcn_mfma_f32_16x16x32_bf16(pf1, onesb, ofl, 0, 0, 0);
      }
    }

    // ---- write partial (unnormalized O + m,l) ----
    #pragma unroll
    for (int r = 0; r < 4; ++r) {
      const int s = q0 + wave*16 + quad*4 + r;
      u16* orow = opart + obase + (size_t)s * 64;
      #pragma unroll
      for (int dht = 0; dht < 4; ++dht) orow[dht*16 + l16] = f2b(of[dht][r]);
      const float lr = __shfl(ofl[r], quad * 16);   // col 0 of this row block
      if (l16 == 0) { ml[mlbase + 2*s] = m[r]; ml[mlbase + 2*s + 1] = lr; }
    }
  }
}

// ---------- combine attention partials -> attnb bf16 [B,S,1024] ----------
__global__ __launch_bounds__(256) void attn_combine_kernel(
    const u16* __restrict__ opart, const float* __restrict__ ml,
    u16* __restrict__ out)
{
  const int t = threadIdx.x;
  const int s = blockIdx.x * 4 + (t >> 6);
  const int lane = t & 63;
  const int h = blockIdx.y, b = blockIdx.z;

  const size_t o0  = ((((size_t)0 * 2 + b) * 16 + h) * 2048 + s) * 64 + lane;
  const size_t o1  = ((((size_t)1 * 2 + b) * 16 + h) * 2048 + s) * 64 + lane;
  const size_t ml0 = ((((size_t)0 * 2 + b) * 16 + h) * 2048 + s) * 2;
  const size_t ml1 = ((((size_t)1 * 2 + b) * 16 + h) * 2048 + s) * 2;

  const float m0 = ml[ml0], l0 = ml[ml0 + 1];
  const float m1 = ml[ml1], l1 = ml[ml1 + 1];
  const float M  = fmaxf(m0, m1);
  const float w0 = exp2f(m0 - M), w1 = exp2f(m1 - M);
  const float L  = w0 * l0 + w1 * l1;
  const float o  = w0 * b2f(opart[o0]) + w1 * b2f(opart[o1]);
  out[((size_t)b * 2048 + s) * 1024 + h * 64 + lane] = f2b(o / L);
}

// ---------- K-split combine: out(fp32) = res + p0 + p1 + bias ----------
// shapes [4096,1024]; p0/p1 bf16 partials (possibly disjoint regions)
__global__ __launch_bounds__(256) void ksplit_combine_kernel(
    const u16* __restrict__ p0, const u16* __restrict__ p1,
    const float* __restrict__ res, const float* __restrict__ bias,
    float* __restrict__ out)
{
  const size_t i0 = ((size_t)blockIdx.x * 256 + threadIdx.x) * 8;
  usx8 a = *(const usx8*)(p0 + i0);
  usx8 c = *(const usx8*)(p1 + i0);
  const int col = (int)(i0 & 1023);
  floatx4 bv0 = *(const floatx4*)(bias + col);
  floatx4 bv1 = *(const floatx4*)(bias + col + 4);
  floatx4 h0 = *(const floatx4*)(res + i0);
  floatx4 h1 = *(const floatx4*)(res + i0 + 4);
  floatx4 o0, o1;
  #pragma unroll
  for (int i = 0; i < 4; ++i) o0[i] = h0[i] + b2f(a[i])   + b2f(c[i])   + bv0[i];
  #pragma unroll
  for (int i = 0; i < 4; ++i) o1[i] = h1[i] + b2f(a[4+i]) + b2f(c[4+i]) + bv1[i];
  *(floatx4*)(out + i0)     = o0;
  *(floatx4*)(out + i0 + 4) = o1;
}

// ---------- launch ----------
extern "C" void kernel_launch(void* const* d_in, const int* in_sizes, int n_in,
                              void* d_out, int out_size, void* d_ws, size_t ws_size,
                              hipStream_t stream) {
  const float* hidden    = (const float*)d_in[0];
  const float* w_attn    = (const float*)d_in[1];
  const float* b_attn    = (const float*)d_in[2];
  const float* w_proj    = (const float*)d_in[3];
  const float* b_proj    = (const float*)d_in[4];
  const float* w_fc      = (const float*)d_in[5];
  const float* b_fc      = (const float*)d_in[6];
  const float* w_fc_proj = (const float*)d_in[7];
  const float* b_fc_proj = (const float*)d_in[8];
  const float* ln1_w     = (const float*)d_in[9];
  const float* ln1_b     = (const float*)d_in[10];
  const float* ln2_w     = (const float*)d_in[11];
  const float* ln2_b     = (const float*)d_in[12];

  // Workspace layout (MB offsets), liveness-checked:
  //  0..24  qkvb          -> yb(0..8) -> fcb(8..40)... see below
  // 24..32  xb            -> opart(24..40) -> pproj(24..40)
  // 40..42  mlbuf
  // 42..50  attnb         -> hbuf(42..58)
  // 50..56  wqT
  // 56..58  wpT
  // 58..66  wfT           -> pfcp1(58..66)
  // 66..74  wfpT
  char* wsb = (char*)d_ws;
  u16*   qkvb  = (u16*)  (wsb + (size_t)( 0u << 20));  // 24 MB [4096,3072]
  u16*   xb    = (u16*)  (wsb + (size_t)(24u << 20));  //  8 MB [4096,1024]
  u16*   opart = (u16*)  (wsb + (size_t)(24u << 20));  // 16 MB (xb dead)
  float* mlbuf = (float*)(wsb + (size_t)(40u << 20));  //  2 MB
  u16*   attnb = (u16*)  (wsb + (size_t)(42u << 20));  //  8 MB [4096,1024]
  u16*   wqT   = (u16*)  (wsb + (size_t)(50u << 20));  //  6 MB [3072,1024]
  u16*   wpT   = (u16*)  (wsb + (size_t)(56u << 20));  //  2 MB [1024,1024]
  u16*   wfT   = (u16*)  (wsb + (size_t)(58u << 20));  //  8 MB [4096,1024]
  u16*   wfpT  = (u16*)  (wsb + (size_t)(66u << 20));  //  8 MB [1024,4096]
  u16*   pproj = (u16*)  (wsb + (size_t)(24u << 20));  // 16 MB (opart dead)
  float* hbuf  = (float*)(wsb + (size_t)(42u << 20));  // 16 MB fp32 (attnb/wqT/wpT dead)
  u16*   yb    = (u16*)  (wsb + (size_t)( 0u << 20));  //  8 MB (qkvb dead)
  u16*   fcb   = (u16*)  (wsb + (size_t)( 8u << 20));  // 32 MB (qkvb/pproj dead)
  u16*   pfcp0 = (u16*)  (wsb + (size_t)( 0u << 20));  //  8 MB (yb dead)
  u16*   pfcp1 = (u16*)  (wsb + (size_t)(58u << 20));  //  8 MB (wfT dead)
  const size_t zstr_fcp = ((size_t)58u << 20) / 2;     // pfcp1 - pfcp0 in u16

  // 0) weight transpose+convert fp32[K,N] -> bf16[N,K]
  wtrans_kernel<<<dim3(96, 32),  256, 0, stream>>>(w_attn,    wqT,  1024, 3072);
  wtrans_kernel<<<dim3(32, 32),  256, 0, stream>>>(w_proj,    wpT,  1024, 1024);
  wtrans_kernel<<<dim3(128, 32), 256, 0, stream>>>(w_fc,      wfT,  1024, 4096);
  wtrans_kernel<<<dim3(32, 128), 256, 0, stream>>>(w_fc_proj, wfpT, 4096, 1024);

  // 1) x = LN1(hidden) -> bf16
  ln_bf16_kernel<<<4096, 256, 0, stream>>>(hidden, ln1_w, ln1_b, xb);
  // 2) qkv = x @ w_attn + b_attn -> bf16; q-cols pre-scaled by C2 (flag 8)
  gemm_mfma_kernel<128,128,12,4><<<dim3(24, 32, 1), 256, 0, stream>>>(
      xb, wqT, b_attn, nullptr, qkvb, 4096, 3072, 1024, 1024, 0);
  // 3) flash attention partials (paired q-tiles, K-split x2) + combine
  attn_mfma_kernel<<<dim3(32, 16, 2), 256, 0, stream>>>(qkvb, opart, mlbuf);
  attn_combine_kernel<<<dim3(512, 16, 2), 256, 0, stream>>>(opart, mlbuf, attnb);
  // 4) proj partials: K-split x2, 128x64 tiles (1024 blocks, 4/CU)
  gemm_mfma_kernel<128,64,4,4><<<dim3(16, 32, 2), 256, 0, stream>>>(
      attnb, wpT, nullptr, nullptr, pproj, 4096, 1024, 1024, 512, 4194304);
  // 4b) h = hidden + p0 + p1 + b_proj -> fp32
  ksplit_combine_kernel<<<dim3(2048), 256, 0, stream>>>(
      pproj, pproj + 4194304, hidden, b_proj, hbuf);
  // 5) y = LN2(h) -> bf16
  ln_bf16_kernel<<<4096, 256, 0, stream>>>(hbuf, ln2_w, ln2_b, yb);
  // 6) fc = gelu(y @ w_fc + b_fc) -> bf16 [4096,4096], 128x128 (1024 blocks)
  gemm_mfma_kernel<128,128,5,4><<<dim3(32, 32, 1), 256, 0, stream>>>(
      yb, wfT, b_fc, nullptr, fcb, 4096, 4096, 1024, 1024, 0);
  // 7) fc_proj partials: K-split x2, 128x64 tiles (1024 blocks)
  gemm_mfma_kernel<128,64,4,4><<<dim3(16, 32, 2), 256, 0, stream>>>(
      fcb, wfpT, nullptr, nullptr, pfcp0, 4096, 1024, 4096, 2048, zstr_fcp);
  // 8) out = h + p0 + p1 + b_fc_proj -> fp32
  ksplit_combine_kernel<<<dim3(2048), 256, 0, stream>>>(
      pfcp0, pfcp1, hbuf, b_fc_proj, (float*)d_out);
}

// Round 7
// 364.072 us; speedup vs baseline: 4.0585x; 1.0499x over previous
//
#include <hip/hip_runtime.h>
#include <cstdint>
#include <cstddef>

// ---------- types ----------
typedef unsigned short u16;
typedef float  floatx4 __attribute__((ext_vector_type(4)));
typedef short  short8  __attribute__((ext_vector_type(8)));
typedef u16    usx4    __attribute__((ext_vector_type(4)));
typedef u16    usx8    __attribute__((ext_vector_type(8)));
typedef unsigned uintx2 __attribute__((ext_vector_type(2)));

// fp32 -> bf16, round-to-nearest-even
__device__ __forceinline__ u16 f2b(float f) {
  unsigned u = __float_as_uint(f);
  unsigned r = u + 0x7fffu + ((u >> 16) & 1u);
  return (u16)(r >> 16);
}
__device__ __forceinline__ float b2f(u16 s) {
  return __uint_as_float(((unsigned)s) << 16);
}

// GPT-2 tanh-gelu, exact algebraic rewrite: 0.5x(1+tanh(u)) = x*sigmoid(2u)
__device__ __forceinline__ float gelu_f(float x) {
  const float k = 2.3022082f;  // 2*sqrt(2/pi)*log2(e)
  float u = x * (1.0f + 0.044715f * x * x);
  float t = __builtin_amdgcn_exp2f(-k * u);
  return x * __builtin_amdgcn_rcpf(1.0f + t);
}

// async global->LDS 16B: lds dst = wave-uniform base + lane*16 (HW rule)
__device__ __forceinline__ void gl2lds16(const u16* g, u16* l) {
  __builtin_amdgcn_global_load_lds(
      (const __attribute__((address_space(1))) unsigned int*)g,
      (__attribute__((address_space(3))) unsigned int*)l, 16, 0, 0);
}

#define C2SCALE 0.18033688011112042f  // (1/8) * log2(e)

// ---------- LayerNorm: one block per row of 1024, bf16 out ----------
__global__ __launch_bounds__(256) void ln_bf16_kernel(
    const float* __restrict__ in, const float* __restrict__ w,
    const float* __restrict__ b, u16* __restrict__ out)
{
  const int row = blockIdx.x;
  const int t = threadIdx.x;
  const float* p = in + (size_t)row * 1024 + t * 4;
  floatx4 v = *(const floatx4*)p;
  float s  = v.x + v.y + v.z + v.w;
  float ss = v.x*v.x + v.y*v.y + v.z*v.z + v.w*v.w;
  #pragma unroll
  for (int m = 1; m < 64; m <<= 1) {
    s  += __shfl_xor(s,  m);
    ss += __shfl_xor(ss, m);
  }
  __shared__ float red[8];
  if ((t & 63) == 0) { red[(t >> 6)*2] = s; red[(t >> 6)*2 + 1] = ss; }
  __syncthreads();
  s  = red[0] + red[2] + red[4] + red[6];
  ss = red[1] + red[3] + red[5] + red[7];
  const float mean = s * (1.0f / 1024.0f);
  const float var  = ss * (1.0f / 1024.0f) - mean * mean;
  const float rstd = rsqrtf(var + 1e-6f);
  floatx4 wv = *(const floatx4*)(w + t * 4);
  floatx4 bv = *(const floatx4*)(b + t * 4);
  usx4 o = { f2b(wv.x * ((v.x - mean) * rstd) + bv.x),
             f2b(wv.y * ((v.y - mean) * rstd) + bv.y),
             f2b(wv.z * ((v.z - mean) * rstd) + bv.z),
             f2b(wv.w * ((v.w - mean) * rstd) + bv.w) };
  *(usx4*)(out + (size_t)row * 1024 + t * 4) = o;
}

// ---------- fused K-split combine + LayerNorm (for h = res+p0+p1+bias) ----
// one block per row of 1024; writes h (fp32) and LN(h) (bf16)
__global__ __launch_bounds__(256) void combine_ln_kernel(
    const u16* __restrict__ p0, const u16* __restrict__ p1,
    const float* __restrict__ res, const float* __restrict__ bias,
    const float* __restrict__ w, const float* __restrict__ b,
    float* __restrict__ hout, u16* __restrict__ yout)
{
  const int row = blockIdx.x;
  const int t = threadIdx.x;
  const size_t i0 = (size_t)row * 1024 + t * 4;
  floatx4 rv = *(const floatx4*)(res + i0);
  usx4 a = *(const usx4*)(p0 + i0);
  usx4 c = *(const usx4*)(p1 + i0);
  floatx4 biasv = *(const floatx4*)(bias + t * 4);
  floatx4 v;
  #pragma unroll
  for (int i = 0; i < 4; ++i) v[i] = rv[i] + b2f(a[i]) + b2f(c[i]) + biasv[i];
  *(floatx4*)(hout + i0) = v;

  float s  = v.x + v.y + v.z + v.w;
  float ss = v.x*v.x + v.y*v.y + v.z*v.z + v.w*v.w;
  #pragma unroll
  for (int m = 1; m < 64; m <<= 1) {
    s  += __shfl_xor(s,  m);
    ss += __shfl_xor(ss, m);
  }
  __shared__ float red[8];
  if ((t & 63) == 0) { red[(t >> 6)*2] = s; red[(t >> 6)*2 + 1] = ss; }
  __syncthreads();
  s  = red[0] + red[2] + red[4] + red[6];
  ss = red[1] + red[3] + red[5] + red[7];
  const float mean = s * (1.0f / 1024.0f);
  const float var  = ss * (1.0f / 1024.0f) - mean * mean;
  const float rstd = rsqrtf(var + 1e-6f);
  floatx4 wv = *(const floatx4*)(w + t * 4);
  floatx4 bv = *(const floatx4*)(b + t * 4);
  usx4 o = { f2b(wv.x * ((v.x - mean) * rstd) + bv.x),
             f2b(wv.y * ((v.y - mean) * rstd) + bv.y),
             f2b(wv.z * ((v.z - mean) * rstd) + bv.z),
             f2b(wv.w * ((v.w - mean) * rstd) + bv.w) };
  *(usx4*)(yout + i0) = o;
}

// ---------- weight transpose+convert: 4 weights in one launch ----------
__device__ __forceinline__ void wtrans_body(
    const float* __restrict__ in, u16* __restrict__ out, int K, int N,
    int bx, int by, int tx, int ty)
{
  __shared__ u16 tile[32][33];
  const int n0 = bx * 32, k0 = by * 32;
  #pragma unroll
  for (int i = 0; i < 4; ++i)
    tile[ty + i*8][tx] = f2b(in[(size_t)(k0 + ty + i*8) * N + n0 + tx]);
  __syncthreads();
  #pragma unroll
  for (int i = 0; i < 4; ++i)
    out[(size_t)(n0 + ty + i*8) * K + k0 + tx] = tile[tx][ty + i*8];
}

__global__ __launch_bounds__(256) void wtrans4_kernel(
    const float* __restrict__ w0, const float* __restrict__ w1,
    const float* __restrict__ w2, const float* __restrict__ w3,
    u16* __restrict__ o0, u16* __restrict__ o1,
    u16* __restrict__ o2, u16* __restrict__ o3)
{
  int blk = blockIdx.x;
  const int tx = threadIdx.x & 31, ty = threadIdx.x >> 5;
  if (blk < 3072) {
    wtrans_body(w0, o0, 1024, 3072, blk % 96, blk / 96, tx, ty);
  } else if (blk < 4096) {
    blk -= 3072; wtrans_body(w1, o1, 1024, 1024, blk % 32, blk / 32, tx, ty);
  } else if (blk < 8192) {
    blk -= 4096; wtrans_body(w2, o2, 1024, 4096, blk % 128, blk / 128, tx, ty);
  } else {
    blk -= 8192; wtrans_body(w3, o3, 4096, 1024, blk % 32, blk / 32, tx, ty);
  }
}

// ---------- GEMM (m97 structure): C[M,N] = A[M,K] @ Bt[N,K]^T ----------
// BMxBN tile, BK=32, 256 threads, 4 waves 2x2, global_load_lds(16B) staging.
// XOR chunk swizzle on the DMA source -> 4-way instead of 8-way LDS conflicts.
// grid.z splits K: kStart = z*kLen; partial z-outputs at Cout + z*zStride.
// FLAGS: 1 = gelu, 2 = +Res (fp32), 4 = bf16 out, 8 = scale cols<1024 by C2
template<int BM, int BN, int FLAGS, int MINW>
__global__ __launch_bounds__(256, MINW) void gemm_mfma_kernel(
    const u16* __restrict__ A, const u16* __restrict__ Bt,
    const float* __restrict__ bias, const float* __restrict__ Res,
    void* __restrict__ Cout, int M, int N, int K, int kLen, size_t zStride)
{
  constexpr int WM = BM / 2, WN = BN / 2;
  constexpr int MT = WM / 16, NT = WN / 16;
  __shared__ u16 As[BM * 32];
  __shared__ u16 Bs[BN * 32];

  const int t = threadIdx.x;
  const int wave = t >> 6, lane = t & 63;
  const int quad = lane >> 4, l16 = lane & 15;
  const int wm = wave >> 1, wn = wave & 1;
  const int bm0 = blockIdx.y * BM, bn0 = blockIdx.x * BN;
  const int kStart = blockIdx.z * kLen;

  const int sRow = lane >> 2;
  const int sq   = (lane & 3) ^ (sRow & 3);

  const u16* aG[BM / 64];
  u16* aL[BM / 64];
  #pragma unroll
  for (int j = 0; j < BM / 64; ++j) {
    const int band = j * 4 + wave;
    aG[j] = A + (size_t)(bm0 + band * 16 + sRow) * K + kStart + sq * 8;
    aL[j] = As + band * 512;
  }
  const u16* bG[BN / 64];
  u16* bL[BN / 64];
  #pragma unroll
  for (int j = 0; j < BN / 64; ++j) {
    const int band = j * 4 + wave;
    bG[j] = Bt + (size_t)(bn0 + band * 16 + sRow) * K + kStart + sq * 8;
    bL[j] = Bs + band * 512;
  }

  floatx4 acc[MT][NT] = {};
  const int rcol = (quad ^ (l16 & 3)) << 3;

  for (int k0 = 0; k0 < kLen; k0 += 32) {
    __syncthreads();
    #pragma unroll
    for (int j = 0; j < BM / 64; ++j) gl2lds16(aG[j] + k0, aL[j]);
    #pragma unroll
    for (int j = 0; j < BN / 64; ++j) gl2lds16(bG[j] + k0, bL[j]);
    __syncthreads();

    short8 af[MT], bf[NT];
    #pragma unroll
    for (int mt = 0; mt < MT; ++mt)
      af[mt] = *(const short8*)&As[(wm*WM + mt*16 + l16) * 32 + rcol];
    #pragma unroll
    for (int nt = 0; nt < NT; ++nt)
      bf[nt] = *(const short8*)&Bs[(wn*WN + nt*16 + l16) * 32 + rcol];
    #pragma unroll
    for (int mt = 0; mt < MT; ++mt)
      #pragma unroll
      for (int nt = 0; nt < NT; ++nt)
        acc[mt][nt] = __builtin_amdgcn_mfma_f32_16x16x32_bf16(af[mt], bf[nt], acc[mt][nt], 0, 0, 0);
  }

  const int orow0 = bm0 + wm * WM;
  const int ocol0 = bn0 + wn * WN;
  const size_t zoff = (size_t)blockIdx.z * zStride;
  #pragma unroll
  for (int nt = 0; nt < NT; ++nt) {
    const int col = ocol0 + nt*16 + l16;
    const float bv = bias ? bias[col] : 0.0f;
    const float postscale = ((FLAGS & 8) && col < 1024) ? C2SCALE : 1.0f;
    #pragma unroll
    for (int mt = 0; mt < MT; ++mt) {
      #pragma unroll
      for (int r = 0; r < 4; ++r) {
        const int row = orow0 + mt*16 + quad*4 + r;
        float v = acc[mt][nt][r] + bv;
        if (FLAGS & 1) v = gelu_f(v);
        if (FLAGS & 8) v *= postscale;
        if (FLAGS & 2) v += Res[(size_t)row * N + col];
        if (FLAGS & 4) ((u16*)Cout)[zoff + (size_t)row * N + col] = f2b(v);
        else           ((float*)Cout)[zoff + (size_t)row * N + col] = v;
      }
    }
  }
}

// ---------- MFMA flash attention (causal), bf16, balanced + K-split ----------
// Q PRE-SCALED by C2; softmax in exp2 domain with native v_exp_f32.
// KEY-INTERLEAVED S mapping: K tile staged so physical row (j&3)*16+(j>>2)
// holds key j => MFMA #kt col l16 = key 4*l16+kt => each lane owns 4
// consecutive keys => packed b64 P writeback (bank-conflict-free).
// grid: (32, H, B): pair = x>>1, half = x&1; q-tiles {pair, 31-pair}.
// opart: [part][b][h][2048][64] bf16 ; ml: [part][b][h][2048][2] fp32
__global__ __launch_bounds__(256, 4) void attn_mfma_kernel(
    const u16* __restrict__ qkv, u16* __restrict__ opart, float* __restrict__ ml)
{
  __shared__ u16 Ks[64][72];  // K tile, key-permuted rows (also Q staging)
  __shared__ u16 Vt[64][72];  // V tile transposed [dh][key] (natural keys)
  __shared__ u16 Ps[64][72];  // P per wave: rows [w*16, w*16+16), natural keys

  const int t    = threadIdx.x;
  const int wave = t >> 6;
  const int lane = t & 63;
  const int quad = lane >> 4;
  const int l16  = lane & 15;
  const int pair = blockIdx.x >> 1;
  const int half = blockIdx.x & 1;
  const int h    = blockIdx.y;
  const int b    = blockIdx.z;

  const size_t base = (size_t)b * 2048 * 3072;
  const int qoff = h * 64;
  const int koff = 1024 + h * 64;
  const int voff = 2048 + h * 64;

  const int prow = t >> 2;                          // phys staging row
  const int scol = (t & 3) * 16;                    // staging col chunk
  const int kmap = ((prow & 15) << 2) | (prow >> 4); // key held by phys row
  const int kpair  = t & 31;        // V staging: keys 2*kpair, 2*kpair+1
  const int vchunk = t >> 5;        // V staging: dh chunk (0..7)

  const size_t obase  = ((((size_t)half * 2 + b) * 16 + h) * 2048) * 64;
  const size_t mlbase = ((((size_t)half * 2 + b) * 16 + h) * 2048) * 2;

  // ones B-fragment: B[0][k]=1.0 — row sums via MFMA
  short8 onesb;
  {
    const short v = (l16 == 0) ? (short)0x3F80 : (short)0;
    #pragma unroll
    for (int i = 0; i < 8; ++i) onesb[i] = v;
  }

  #pragma unroll 1
  for (int iter = 0; iter < 2; ++iter) {
    const int qi = iter ? (31 - pair) : pair;
    const int q0 = qi << 6;
    const int T  = qi + 1;
    const int mid = (T + 1) >> 1;
    const int t0 = half ? mid : 0;
    const int t1 = half ? T : mid;

    floatx4 of[4] = {};
    floatx4 ofl = {};
    float m[4];
    #pragma unroll
    for (int r = 0; r < 4; ++r) m[r] = -1e30f;

    if (t0 < t1) {
      // ---- stage Q (natural rows) into Ks, grab per-wave A-fragments ----
      __syncthreads();
      {
        const u16* qp = qkv + base + (size_t)(q0 + prow) * 3072 + qoff + scol;
        *(usx8*)&Ks[prow][scol]     = *(const usx8*)qp;
        *(usx8*)&Ks[prow][scol + 8] = *(const usx8*)(qp + 8);
      }
      __syncthreads();
      const short8 qf0 = *(const short8*)&Ks[wave*16 + l16][quad*8];
      const short8 qf1 = *(const short8*)&Ks[wave*16 + l16][32 + quad*8];

      // ---- prefetch first K/V tile (K via key-permuted source row) ----
      usx8 kr0, kr1, vr0, vr1;
      {
        const int k0 = t0 << 6;
        const u16* kp = qkv + base + (size_t)(k0 + kmap) * 3072 + koff + scol;
        kr0 = *(const usx8*)kp; kr1 = *(const usx8*)(kp + 8);
        const u16* vp = qkv + base + (size_t)(k0 + 2*kpair) * 3072 + voff + vchunk*8;
        vr0 = *(const usx8*)vp; vr1 = *(const usx8*)(vp + 3072);
      }

      for (int tIdx = t0; tIdx < t1; ++tIdx) {
        __syncthreads();
        *(usx8*)&Ks[prow][scol]     = kr0;
        *(usx8*)&Ks[prow][scol + 8] = kr1;
        #pragma unroll
        for (int i = 0; i < 8; ++i)
          *(unsigned*)&Vt[vchunk*8 + i][2*kpair] =
              (unsigned)vr0[i] | ((unsigned)vr1[i] << 16);
        __syncthreads();

        if (tIdx + 1 < t1) {
          const int kn = (tIdx + 1) << 6;
          const u16* kp = qkv + base + (size_t)(kn + kmap) * 3072 + koff + scol;
          kr0 = *(const usx8*)kp; kr1 = *(const usx8*)(kp + 8);
          const u16* vp = qkv + base + (size_t)(kn + 2*kpair) * 3072 + voff + vchunk*8;
          vr0 = *(const usx8*)vp; vr1 = *(const usx8*)(vp + 3072);
        }

        // ---- S = Q K^T ; mfma kt: col l16 = key 4*l16+kt ----
        const int k0 = tIdx << 6;
        floatx4 sf[4];
        #pragma unroll
        for (int kt = 0; kt < 4; ++kt) {
          short8 kf0 = *(const short8*)&Ks[kt*16 + l16][quad*8];
          short8 kf1 = *(const short8*)&Ks[kt*16 + l16][32 + quad*8];
          floatx4 z = {};
          z      = __builtin_amdgcn_mfma_f32_16x16x32_bf16(qf0, kf0, z, 0, 0, 0);
          sf[kt] = __builtin_amdgcn_mfma_f32_16x16x32_bf16(qf1, kf1, z, 0, 0, 0);
        }

        // ---- online softmax ----
        const bool diag = (tIdx == qi);
        #pragma unroll
        for (int r = 0; r < 4; ++r) {
          float sv0 = sf[0][r], sv1 = sf[1][r], sv2 = sf[2][r], sv3 = sf[3][r];
          if (diag) {
            const int qrow = q0 + wave*16 + quad*4 + r;
            const int kbase = k0 + 4*l16;
            if (kbase     > qrow) sv0 = -1e30f;
            if (kbase + 1 > qrow) sv1 = -1e30f;
            if (kbase + 2 > qrow) sv2 = -1e30f;
            if (kbase + 3 > qrow) sv3 = -1e30f;
          }
          float mx = fmaxf(fmaxf(sv0, sv1), fmaxf(sv2, sv3));
          #pragma unroll
          for (int msk = 1; msk < 16; msk <<= 1) mx = fmaxf(mx, __shfl_xor(mx, msk, 16));
          const float nm = fmaxf(m[r], mx);
          const float alpha = __builtin_amdgcn_exp2f(m[r] - nm);
          m[r] = nm;
          const unsigned e0 = f2b(__builtin_amdgcn_exp2f(sv0 - nm));
          const unsigned e1 = f2b(__builtin_amdgcn_exp2f(sv1 - nm));
          const unsigned e2 = f2b(__builtin_amdgcn_exp2f(sv2 - nm));
          const unsigned e3 = f2b(__builtin_amdgcn_exp2f(sv3 - nm));
          uintx2 pw = { e0 | (e1 << 16), e2 | (e3 << 16) };
          *(uintx2*)&Ps[wave*16 + quad*4 + r][l16 * 4] = pw;
          #pragma unroll
          for (int dht = 0; dht < 4; ++dht) of[dht][r] *= alpha;
          ofl[r] *= alpha;
        }

        // ---- O += P V ; l += P 1 (natural key order on both sides) ----
        short8 pf0 = *(const short8*)&Ps[wave*16 + l16][quad*8];
        short8 pf1 = *(const short8*)&Ps[wave*16 + l16][32 + quad*8];
        #pragma unroll
        for (int dht = 0; dht < 4; ++dht) {
          short8 vf0 = *(const short8*)&Vt[dht*16 + l16][quad*8];
          short8 vf1 = *(const short8*)&Vt[dht*16 + l16][32 + quad*8];
          of[dht] = __builtin_amdgcn_mfma_f32_16x16x32_bf16(pf0, vf0, of[dht], 0, 0, 0);
          of[dht] = __builtin_amdgcn_mfma_f32_16x16x32_bf16(pf1, vf1, of[dht], 0, 0, 0);
        }
        ofl = __builtin_amdgcn_mfma_f32_16x16x32_bf16(pf0, onesb, ofl, 0, 0, 0);
        ofl = __builtin_amdgcn_mfma_f32_16x16x32_bf16(pf1, onesb, ofl, 0, 0, 0);
      }
    }

    // ---- write partial (unnormalized O + m,l) ----
    #pragma unroll
    for (int r = 0; r < 4; ++r) {
      const int s = q0 + wave*16 + quad*4 + r;
      u16* orow = opart + obase + (size_t)s * 64;
      #pragma unroll
      for (int dht = 0; dht < 4; ++dht) orow[dht*16 + l16] = f2b(of[dht][r]);
      const float lr = __shfl(ofl[r], quad * 16);
      if (l16 == 0) { ml[mlbase + 2*s] = m[r]; ml[mlbase + 2*s + 1] = lr; }
    }
  }
}

// ---------- combine attention partials -> attnb bf16 [B,S,1024] ----------
__global__ __launch_bounds__(256) void attn_combine_kernel(
    const u16* __restrict__ opart, const float* __restrict__ ml,
    u16* __restrict__ out)
{
  const int t = threadIdx.x;
  const int s = blockIdx.x * 4 + (t >> 6);
  const int lane = t & 63;
  const int h = blockIdx.y, b = blockIdx.z;

  const size_t o0  = ((((size_t)0 * 2 + b) * 16 + h) * 2048 + s) * 64 + lane;
  const size_t o1  = ((((size_t)1 * 2 + b) * 16 + h) * 2048 + s) * 64 + lane;
  const size_t ml0 = ((((size_t)0 * 2 + b) * 16 + h) * 2048 + s) * 2;
  const size_t ml1 = ((((size_t)1 * 2 + b) * 16 + h) * 2048 + s) * 2;

  const float m0 = ml[ml0], l0 = ml[ml0 + 1];
  const float m1 = ml[ml1], l1 = ml[ml1 + 1];
  const float M  = fmaxf(m0, m1);
  const float w0 = __builtin_amdgcn_exp2f(m0 - M);
  const float w1 = __builtin_amdgcn_exp2f(m1 - M);
  const float L  = w0 * l0 + w1 * l1;
  const float o  = w0 * b2f(opart[o0]) + w1 * b2f(opart[o1]);
  out[((size_t)b * 2048 + s) * 1024 + h * 64 + lane] = f2b(o / L);
}

// ---------- K-split combine: out(fp32) = res + p0 + p1 + bias ----------
__global__ __launch_bounds__(256) void ksplit_combine_kernel(
    const u16* __restrict__ p0, const u16* __restrict__ p1,
    const float* __restrict__ res, const float* __restrict__ bias,
    float* __restrict__ out)
{
  const size_t i0 = ((size_t)blockIdx.x * 256 + threadIdx.x) * 8;
  usx8 a = *(const usx8*)(p0 + i0);
  usx8 c = *(const usx8*)(p1 + i0);
  const int col = (int)(i0 & 1023);
  floatx4 bv0 = *(const floatx4*)(bias + col);
  floatx4 bv1 = *(const floatx4*)(bias + col + 4);
  floatx4 h0 = *(const floatx4*)(res + i0);
  floatx4 h1 = *(const floatx4*)(res + i0 + 4);
  floatx4 o0, o1;
  #pragma unroll
  for (int i = 0; i < 4; ++i) o0[i] = h0[i] + b2f(a[i])   + b2f(c[i])   + bv0[i];
  #pragma unroll
  for (int i = 0; i < 4; ++i) o1[i] = h1[i] + b2f(a[4+i]) + b2f(c[4+i]) + bv1[i];
  *(floatx4*)(out + i0)     = o0;
  *(floatx4*)(out + i0 + 4) = o1;
}

// ---------- launch ----------
extern "C" void kernel_launch(void* const* d_in, const int* in_sizes, int n_in,
                              void* d_out, int out_size, void* d_ws, size_t ws_size,
                              hipStream_t stream) {
  const float* hidden    = (const float*)d_in[0];
  const float* w_attn    = (const float*)d_in[1];
  const float* b_attn    = (const float*)d_in[2];
  const float* w_proj    = (const float*)d_in[3];
  const float* b_proj    = (const float*)d_in[4];
  const float* w_fc      = (const float*)d_in[5];
  const float* b_fc      = (const float*)d_in[6];
  const float* w_fc_proj = (const float*)d_in[7];
  const float* b_fc_proj = (const float*)d_in[8];
  const float* ln1_w     = (const float*)d_in[9];
  const float* ln1_b     = (const float*)d_in[10];
  const float* ln2_w     = (const float*)d_in[11];
  const float* ln2_b     = (const float*)d_in[12];

  // Workspace layout (MB offsets), liveness-checked (see round-6 notes)
  char* wsb = (char*)d_ws;
  u16*   qkvb  = (u16*)  (wsb + (size_t)( 0u << 20));  // 24 MB [4096,3072]
  u16*   xb    = (u16*)  (wsb + (size_t)(24u << 20));  //  8 MB [4096,1024]
  u16*   opart = (u16*)  (wsb + (size_t)(24u << 20));  // 16 MB (xb dead)
  float* mlbuf = (float*)(wsb + (size_t)(40u << 20));  //  2 MB
  u16*   attnb = (u16*)  (wsb + (size_t)(42u << 20));  //  8 MB [4096,1024]
  u16*   wqT   = (u16*)  (wsb + (size_t)(50u << 20));  //  6 MB [3072,1024]
  u16*   wpT   = (u16*)  (wsb + (size_t)(56u << 20));  //  2 MB [1024,1024]
  u16*   wfT   = (u16*)  (wsb + (size_t)(58u << 20));  //  8 MB [4096,1024]
  u16*   wfpT  = (u16*)  (wsb + (size_t)(66u << 20));  //  8 MB [1024,4096]
  u16*   pproj = (u16*)  (wsb + (size_t)(24u << 20));  // 16 MB (opart dead)
  float* hbuf  = (float*)(wsb + (size_t)(42u << 20));  // 16 MB fp32
  u16*   yb    = (u16*)  (wsb + (size_t)( 0u << 20));  //  8 MB (qkvb dead)
  u16*   fcb   = (u16*)  (wsb + (size_t)( 8u << 20));  // 32 MB
  u16*   pfcp0 = (u16*)  (wsb + (size_t)( 0u << 20));  //  8 MB (yb dead)
  u16*   pfcp1 = (u16*)  (wsb + (size_t)(58u << 20));  //  8 MB (wfT dead)
  const size_t zstr_fcp = ((size_t)58u << 20) / 2;

  // 0) weight transpose+convert (single launch)
  wtrans4_kernel<<<dim3(12288), 256, 0, stream>>>(
      w_attn, w_proj, w_fc, w_fc_proj, wqT, wpT, wfT, wfpT);

  // 1) x = LN1(hidden) -> bf16
  ln_bf16_kernel<<<4096, 256, 0, stream>>>(hidden, ln1_w, ln1_b, xb);
  // 2) qkv = x @ w_attn + b_attn -> bf16; q-cols pre-scaled by C2 (flag 8)
  gemm_mfma_kernel<128,128,12,4><<<dim3(24, 32, 1), 256, 0, stream>>>(
      xb, wqT, b_attn, nullptr, qkvb, 4096, 3072, 1024, 1024, 0);
  // 3) flash attention partials + combine
  attn_mfma_kernel<<<dim3(32, 16, 2), 256, 0, stream>>>(qkvb, opart, mlbuf);
  attn_combine_kernel<<<dim3(512, 16, 2), 256, 0, stream>>>(opart, mlbuf, attnb);
  // 4) proj partials: K-split x2, 128x64 tiles (1024 blocks)
  gemm_mfma_kernel<128,64,4,4><<<dim3(16, 32, 2), 256, 0, stream>>>(
      attnb, wpT, nullptr, nullptr, pproj, 4096, 1024, 1024, 512, 4194304);
  // 4b+5) h = hidden + p0 + p1 + b_proj; y = LN2(h)  (fused)
  combine_ln_kernel<<<4096, 256, 0, stream>>>(
      pproj, pproj + 4194304, hidden, b_proj, ln2_w, ln2_b, hbuf, yb);
  // 6) fc = gelu(y @ w_fc + b_fc) -> bf16, 128x128 (1024 blocks)
  gemm_mfma_kernel<128,128,5,4><<<dim3(32, 32, 1), 256, 0, stream>>>(
      yb, wfT, b_fc, nullptr, fcb, 4096, 4096, 1024, 1024, 0);
  // 7) fc_proj partials: K-split x2, 128x64 tiles (1024 blocks)
  gemm_mfma_kernel<128,64,4,4><<<dim3(16, 32, 2), 256, 0, stream>>>(
      fcb, wfpT, nullptr, nullptr, pfcp0, 4096, 1024, 4096, 2048, zstr_fcp);
  // 8) out = h + p0 + p1 + b_fc_proj -> fp32
  ksplit_combine_kernel<<<dim3(2048), 256, 0, stream>>>(
      pfcp0, pfcp1, hbuf, b_fc_proj, (float*)d_out);
}

// Round 8
// 360.557 us; speedup vs baseline: 4.0981x; 1.0097x over previous
//
#include <hip/hip_runtime.h>
#include <cstdint>
#include <cstddef>

// ---------- types ----------
typedef unsigned short u16;
typedef float  floatx4 __attribute__((ext_vector_type(4)));
typedef short  short8  __attribute__((ext_vector_type(8)));
typedef u16    usx4    __attribute__((ext_vector_type(4)));
typedef u16    usx8    __attribute__((ext_vector_type(8)));
typedef unsigned uintx2 __attribute__((ext_vector_type(2)));

// fp32 -> bf16, round-to-nearest-even
__device__ __forceinline__ u16 f2b(float f) {
  unsigned u = __float_as_uint(f);
  unsigned r = u + 0x7fffu + ((u >> 16) & 1u);
  return (u16)(r >> 16);
}
__device__ __forceinline__ float b2f(u16 s) {
  return __uint_as_float(((unsigned)s) << 16);
}

// GPT-2 tanh-gelu, exact algebraic rewrite: 0.5x(1+tanh(u)) = x*sigmoid(2u)
__device__ __forceinline__ float gelu_f(float x) {
  const float k = 2.3022082f;  // 2*sqrt(2/pi)*log2(e)
  float u = x * (1.0f + 0.044715f * x * x);
  float t = __builtin_amdgcn_exp2f(-k * u);
  return x * __builtin_amdgcn_rcpf(1.0f + t);
}

// async global->LDS 16B: lds dst = wave-uniform base + lane*16 (HW rule)
__device__ __forceinline__ void gl2lds16(const u16* g, u16* l) {
  __builtin_amdgcn_global_load_lds(
      (const __attribute__((address_space(1))) unsigned int*)g,
      (__attribute__((address_space(3))) unsigned int*)l, 16, 0, 0);
}

#define C2SCALE 0.18033688011112042f  // (1/8) * log2(e)

// ---------- LayerNorm: one block per row of 1024, bf16 out ----------
__global__ __launch_bounds__(256) void ln_bf16_kernel(
    const float* __restrict__ in, const float* __restrict__ w,
    const float* __restrict__ b, u16* __restrict__ out)
{
  const int row = blockIdx.x;
  const int t = threadIdx.x;
  const float* p = in + (size_t)row * 1024 + t * 4;
  floatx4 v = *(const floatx4*)p;
  float s  = v.x + v.y + v.z + v.w;
  float ss = v.x*v.x + v.y*v.y + v.z*v.z + v.w*v.w;
  #pragma unroll
  for (int m = 1; m < 64; m <<= 1) {
    s  += __shfl_xor(s,  m);
    ss += __shfl_xor(ss, m);
  }
  __shared__ float red[8];
  if ((t & 63) == 0) { red[(t >> 6)*2] = s; red[(t >> 6)*2 + 1] = ss; }
  __syncthreads();
  s  = red[0] + red[2] + red[4] + red[6];
  ss = red[1] + red[3] + red[5] + red[7];
  const float mean = s * (1.0f / 1024.0f);
  const float var  = ss * (1.0f / 1024.0f) - mean * mean;
  const float rstd = rsqrtf(var + 1e-6f);
  floatx4 wv = *(const floatx4*)(w + t * 4);
  floatx4 bv = *(const floatx4*)(b + t * 4);
  usx4 o = { f2b(wv.x * ((v.x - mean) * rstd) + bv.x),
             f2b(wv.y * ((v.y - mean) * rstd) + bv.y),
             f2b(wv.z * ((v.z - mean) * rstd) + bv.z),
             f2b(wv.w * ((v.w - mean) * rstd) + bv.w) };
  *(usx4*)(out + (size_t)row * 1024 + t * 4) = o;
}

// ---------- fused K-split combine + LayerNorm ----------
__global__ __launch_bounds__(256) void combine_ln_kernel(
    const u16* __restrict__ p0, const u16* __restrict__ p1,
    const float* __restrict__ res, const float* __restrict__ bias,
    const float* __restrict__ w, const float* __restrict__ b,
    float* __restrict__ hout, u16* __restrict__ yout)
{
  const int row = blockIdx.x;
  const int t = threadIdx.x;
  const size_t i0 = (size_t)row * 1024 + t * 4;
  floatx4 rv = *(const floatx4*)(res + i0);
  usx4 a = *(const usx4*)(p0 + i0);
  usx4 c = *(const usx4*)(p1 + i0);
  floatx4 biasv = *(const floatx4*)(bias + t * 4);
  floatx4 v;
  #pragma unroll
  for (int i = 0; i < 4; ++i) v[i] = rv[i] + b2f(a[i]) + b2f(c[i]) + biasv[i];
  *(floatx4*)(hout + i0) = v;

  float s  = v.x + v.y + v.z + v.w;
  float ss = v.x*v.x + v.y*v.y + v.z*v.z + v.w*v.w;
  #pragma unroll
  for (int m = 1; m < 64; m <<= 1) {
    s  += __shfl_xor(s,  m);
    ss += __shfl_xor(ss, m);
  }
  __shared__ float red[8];
  if ((t & 63) == 0) { red[(t >> 6)*2] = s; red[(t >> 6)*2 + 1] = ss; }
  __syncthreads();
  s  = red[0] + red[2] + red[4] + red[6];
  ss = red[1] + red[3] + red[5] + red[7];
  const float mean = s * (1.0f / 1024.0f);
  const float var  = ss * (1.0f / 1024.0f) - mean * mean;
  const float rstd = rsqrtf(var + 1e-6f);
  floatx4 wv = *(const floatx4*)(w + t * 4);
  floatx4 bv = *(const floatx4*)(b + t * 4);
  usx4 o = { f2b(wv.x * ((v.x - mean) * rstd) + bv.x),
             f2b(wv.y * ((v.y - mean) * rstd) + bv.y),
             f2b(wv.z * ((v.z - mean) * rstd) + bv.z),
             f2b(wv.w * ((v.w - mean) * rstd) + bv.w) };
  *(usx4*)(yout + i0) = o;
}

// ---------- weight transpose+convert: 4 weights in one launch ----------
__device__ __forceinline__ void wtrans_body(
    const float* __restrict__ in, u16* __restrict__ out, int K, int N,
    int bx, int by, int tx, int ty)
{
  __shared__ u16 tile[32][33];
  const int n0 = bx * 32, k0 = by * 32;
  #pragma unroll
  for (int i = 0; i < 4; ++i)
    tile[ty + i*8][tx] = f2b(in[(size_t)(k0 + ty + i*8) * N + n0 + tx]);
  __syncthreads();
  #pragma unroll
  for (int i = 0; i < 4; ++i)
    out[(size_t)(n0 + ty + i*8) * K + k0 + tx] = tile[tx][ty + i*8];
}

__global__ __launch_bounds__(256) void wtrans4_kernel(
    const float* __restrict__ w0, const float* __restrict__ w1,
    const float* __restrict__ w2, const float* __restrict__ w3,
    u16* __restrict__ o0, u16* __restrict__ o1,
    u16* __restrict__ o2, u16* __restrict__ o3)
{
  int blk = blockIdx.x;
  const int tx = threadIdx.x & 31, ty = threadIdx.x >> 5;
  if (blk < 3072) {
    wtrans_body(w0, o0, 1024, 3072, blk % 96, blk / 96, tx, ty);
  } else if (blk < 4096) {
    blk -= 3072; wtrans_body(w1, o1, 1024, 1024, blk % 32, blk / 32, tx, ty);
  } else if (blk < 8192) {
    blk -= 4096; wtrans_body(w2, o2, 1024, 4096, blk % 128, blk / 128, tx, ty);
  } else {
    blk -= 8192; wtrans_body(w3, o3, 4096, 1024, blk % 32, blk / 32, tx, ty);
  }
}

// ---------- GEMM (m97 structure): C[M,N] = A[M,K] @ Bt[N,K]^T ----------
// BMxBN tile, BK=32, 256 threads, 4 waves 2x2, global_load_lds(16B) staging.
// LDS XOR swizzle keyed on l16>>2 -> frag reads 2-way (free) bank pattern.
// XCD swizzle: grid (NX,NY,NZ) split into 8 regions (RX x RY x RZ); tile
// (lin%8) picks the region so each XCD streams a compact A/B working set.
// grid.z splits K: kStart = z*kLen; partial z-outputs at Cout + z*zStride.
// FLAGS: 1 = gelu, 2 = +Res (fp32), 4 = bf16 out, 8 = scale cols<1024 by C2
template<int BM, int BN, int FLAGS, int MINW,
         int NX, int NY, int NZ, int RX, int RY, int RZ>
__global__ __launch_bounds__(256, MINW) void gemm_mfma_kernel(
    const u16* __restrict__ A, const u16* __restrict__ Bt,
    const float* __restrict__ bias, const float* __restrict__ Res,
    void* __restrict__ Cout, int M, int N, int K, int kLen, size_t zStride)
{
  constexpr int WM = BM / 2, WN = BN / 2;
  constexpr int MT = WM / 16, NT = WN / 16;
  constexpr int GX = NX / RX, GY = NY / RY, GZ = NZ / RZ;
  __shared__ u16 As[BM * 32];
  __shared__ u16 Bs[BN * 32];

  // ---- XCD-aware tile remap ----
  const int lin = blockIdx.x + NX * (blockIdx.y + NY * blockIdx.z);
  const int xcd = lin & 7;
  const int idx = lin >> 3;
  const int rx = xcd % RX, ry = (xcd / RX) % RY, rz = xcd / (RX * RY);
  const int bx = rx * GX + idx % GX;
  const int by = ry * GY + (idx / GX) % GY;
  const int bz = rz * GZ + idx / (GX * GY);

  const int t = threadIdx.x;
  const int wave = t >> 6, lane = t & 63;
  const int quad = lane >> 4, l16 = lane & 15;
  const int wm = wave >> 1, wn = wave & 1;
  const int bm0 = by * BM, bn0 = bx * BN;
  const int kStart = bz * kLen;

  // staging: lane -> band row lane>>2, LDS chunk lane&3; fetch global chunk
  // (lane&3) ^ ((lane>>4)&3) so LDS[r][c] = G[r][c ^ (r>>2)].
  const int sRow = lane >> 2;
  const int sq   = (lane & 3) ^ ((lane >> 4) & 3);

  const u16* aG[BM / 64];
  u16* aL[BM / 64];
  #pragma unroll
  for (int j = 0; j < BM / 64; ++j) {
    const int band = j * 4 + wave;
    aG[j] = A + (size_t)(bm0 + band * 16 + sRow) * K + kStart + sq * 8;
    aL[j] = As + band * 512;
  }
  const u16* bG[BN / 64];
  u16* bL[BN / 64];
  #pragma unroll
  for (int j = 0; j < BN / 64; ++j) {
    const int band = j * 4 + wave;
    bG[j] = Bt + (size_t)(bn0 + band * 16 + sRow) * K + kStart + sq * 8;
    bL[j] = Bs + band * 512;
  }

  floatx4 acc[MT][NT] = {};
  const int rcol = (quad ^ (l16 >> 2)) << 3;   // 2-way (free) bank pattern

  for (int k0 = 0; k0 < kLen; k0 += 32) {
    __syncthreads();
    #pragma unroll
    for (int j = 0; j < BM / 64; ++j) gl2lds16(aG[j] + k0, aL[j]);
    #pragma unroll
    for (int j = 0; j < BN / 64; ++j) gl2lds16(bG[j] + k0, bL[j]);
    __syncthreads();

    short8 af[MT], bf[NT];
    #pragma unroll
    for (int mt = 0; mt < MT; ++mt)
      af[mt] = *(const short8*)&As[(wm*WM + mt*16 + l16) * 32 + rcol];
    #pragma unroll
    for (int nt = 0; nt < NT; ++nt)
      bf[nt] = *(const short8*)&Bs[(wn*WN + nt*16 + l16) * 32 + rcol];
    #pragma unroll
    for (int mt = 0; mt < MT; ++mt)
      #pragma unroll
      for (int nt = 0; nt < NT; ++nt)
        acc[mt][nt] = __builtin_amdgcn_mfma_f32_16x16x32_bf16(af[mt], bf[nt], acc[mt][nt], 0, 0, 0);
  }

  const int orow0 = bm0 + wm * WM;
  const int ocol0 = bn0 + wn * WN;
  const size_t zoff = (size_t)bz * zStride;
  #pragma unroll
  for (int nt = 0; nt < NT; ++nt) {
    const int col = ocol0 + nt*16 + l16;
    const float bv = bias ? bias[col] : 0.0f;
    const float postscale = ((FLAGS & 8) && col < 1024) ? C2SCALE : 1.0f;
    #pragma unroll
    for (int mt = 0; mt < MT; ++mt) {
      #pragma unroll
      for (int r = 0; r < 4; ++r) {
        const int row = orow0 + mt*16 + quad*4 + r;
        float v = acc[mt][nt][r] + bv;
        if (FLAGS & 1) v = gelu_f(v);
        if (FLAGS & 8) v *= postscale;
        if (FLAGS & 2) v += Res[(size_t)row * N + col];
        if (FLAGS & 4) ((u16*)Cout)[zoff + (size_t)row * N + col] = f2b(v);
        else           ((float*)Cout)[zoff + (size_t)row * N + col] = v;
      }
    }
  }
}

// ---------- MFMA flash attention (causal), bf16, balanced + K-split ----------
// Q PRE-SCALED by C2; softmax in exp2 domain with native v_exp_f32.
// Key-interleaved S mapping -> packed b64 P writeback.
// opart: [part][b][h][2048][64] bf16 ; ml: [part][b][h][2048][2] fp32
__global__ __launch_bounds__(256, 4) void attn_mfma_kernel(
    const u16* __restrict__ qkv, u16* __restrict__ opart, float* __restrict__ ml)
{
  __shared__ u16 Ks[64][72];  // K tile, key-permuted rows (also Q staging)
  __shared__ u16 Vt[64][72];  // V tile transposed [dh][key]
  __shared__ u16 Ps[64][72];  // P per wave

  const int t    = threadIdx.x;
  const int wave = t >> 6;
  const int lane = t & 63;
  const int quad = lane >> 4;
  const int l16  = lane & 15;
  const int pair = blockIdx.x >> 1;
  const int half = blockIdx.x & 1;
  const int h    = blockIdx.y;
  const int b    = blockIdx.z;

  const size_t base = (size_t)b * 2048 * 3072;
  const int qoff = h * 64;
  const int koff = 1024 + h * 64;
  const int voff = 2048 + h * 64;

  const int prow = t >> 2;
  const int scol = (t & 3) * 16;
  const int kmap = ((prow & 15) << 2) | (prow >> 4);
  const int kpair  = t & 31;
  const int vchunk = t >> 5;

  const size_t obase  = ((((size_t)half * 2 + b) * 16 + h) * 2048) * 64;
  const size_t mlbase = ((((size_t)half * 2 + b) * 16 + h) * 2048) * 2;

  short8 onesb;
  {
    const short v = (l16 == 0) ? (short)0x3F80 : (short)0;
    #pragma unroll
    for (int i = 0; i < 8; ++i) onesb[i] = v;
  }

  #pragma unroll 1
  for (int iter = 0; iter < 2; ++iter) {
    const int qi = iter ? (31 - pair) : pair;
    const int q0 = qi << 6;
    const int T  = qi + 1;
    const int mid = (T + 1) >> 1;
    const int t0 = half ? mid : 0;
    const int t1 = half ? T : mid;

    floatx4 of[4] = {};
    floatx4 ofl = {};
    float m[4];
    #pragma unroll
    for (int r = 0; r < 4; ++r) m[r] = -1e30f;

    if (t0 < t1) {
      __syncthreads();
      {
        const u16* qp = qkv + base + (size_t)(q0 + prow) * 3072 + qoff + scol;
        *(usx8*)&Ks[prow][scol]     = *(const usx8*)qp;
        *(usx8*)&Ks[prow][scol + 8] = *(const usx8*)(qp + 8);
      }
      __syncthreads();
      const short8 qf0 = *(const short8*)&Ks[wave*16 + l16][quad*8];
      const short8 qf1 = *(const short8*)&Ks[wave*16 + l16][32 + quad*8];

      usx8 kr0, kr1, vr0, vr1;
      {
        const int k0 = t0 << 6;
        const u16* kp = qkv + base + (size_t)(k0 + kmap) * 3072 + koff + scol;
        kr0 = *(const usx8*)kp; kr1 = *(const usx8*)(kp + 8);
        const u16* vp = qkv + base + (size_t)(k0 + 2*kpair) * 3072 + voff + vchunk*8;
        vr0 = *(const usx8*)vp; vr1 = *(const usx8*)(vp + 3072);
      }

      for (int tIdx = t0; tIdx < t1; ++tIdx) {
        __syncthreads();
        *(usx8*)&Ks[prow][scol]     = kr0;
        *(usx8*)&Ks[prow][scol + 8] = kr1;
        #pragma unroll
        for (int i = 0; i < 8; ++i)
          *(unsigned*)&Vt[vchunk*8 + i][2*kpair] =
              (unsigned)vr0[i] | ((unsigned)vr1[i] << 16);
        __syncthreads();

        if (tIdx + 1 < t1) {
          const int kn = (tIdx + 1) << 6;
          const u16* kp = qkv + base + (size_t)(kn + kmap) * 3072 + koff + scol;
          kr0 = *(const usx8*)kp; kr1 = *(const usx8*)(kp + 8);
          const u16* vp = qkv + base + (size_t)(kn + 2*kpair) * 3072 + voff + vchunk*8;
          vr0 = *(const usx8*)vp; vr1 = *(const usx8*)(vp + 3072);
        }

        const int k0 = tIdx << 6;
        floatx4 sf[4];
        #pragma unroll
        for (int kt = 0; kt < 4; ++kt) {
          short8 kf0 = *(const short8*)&Ks[kt*16 + l16][quad*8];
          short8 kf1 = *(const short8*)&Ks[kt*16 + l16][32 + quad*8];
          floatx4 z = {};
          z      = __builtin_amdgcn_mfma_f32_16x16x32_bf16(qf0, kf0, z, 0, 0, 0);
          sf[kt] = __builtin_amdgcn_mfma_f32_16x16x32_bf16(qf1, kf1, z, 0, 0, 0);
        }

        const bool diag = (tIdx == qi);
        #pragma unroll
        for (int r = 0; r < 4; ++r) {
          float sv0 = sf[0][r], sv1 = sf[1][r], sv2 = sf[2][r], sv3 = sf[3][r];
          if (diag) {
            const int qrow = q0 + wave*16 + quad*4 + r;
            const int kbase = k0 + 4*l16;
            if (kbase     > qrow) sv0 = -1e30f;
            if (kbase + 1 > qrow) sv1 = -1e30f;
            if (kbase + 2 > qrow) sv2 = -1e30f;
            if (kbase + 3 > qrow) sv3 = -1e30f;
          }
          float mx = fmaxf(fmaxf(sv0, sv1), fmaxf(sv2, sv3));
          #pragma unroll
          for (int msk = 1; msk < 16; msk <<= 1) mx = fmaxf(mx, __shfl_xor(mx, msk, 16));
          const float nm = fmaxf(m[r], mx);
          const float alpha = __builtin_amdgcn_exp2f(m[r] - nm);
          m[r] = nm;
          const unsigned e0 = f2b(__builtin_amdgcn_exp2f(sv0 - nm));
          const unsigned e1 = f2b(__builtin_amdgcn_exp2f(sv1 - nm));
          const unsigned e2 = f2b(__builtin_amdgcn_exp2f(sv2 - nm));
          const unsigned e3 = f2b(__builtin_amdgcn_exp2f(sv3 - nm));
          uintx2 pw = { e0 | (e1 << 16), e2 | (e3 << 16) };
          *(uintx2*)&Ps[wave*16 + quad*4 + r][l16 * 4] = pw;
          #pragma unroll
          for (int dht = 0; dht < 4; ++dht) of[dht][r] *= alpha;
          ofl[r] *= alpha;
        }

        short8 pf0 = *(const short8*)&Ps[wave*16 + l16][quad*8];
        short8 pf1 = *(const short8*)&Ps[wave*16 + l16][32 + quad*8];
        #pragma unroll
        for (int dht = 0; dht < 4; ++dht) {
          short8 vf0 = *(const short8*)&Vt[dht*16 + l16][quad*8];
          short8 vf1 = *(const short8*)&Vt[dht*16 + l16][32 + quad*8];
          of[dht] = __builtin_amdgcn_mfma_f32_16x16x32_bf16(pf0, vf0, of[dht], 0, 0, 0);
          of[dht] = __builtin_amdgcn_mfma_f32_16x16x32_bf16(pf1, vf1, of[dht], 0, 0, 0);
        }
        ofl = __builtin_amdgcn_mfma_f32_16x16x32_bf16(pf0, onesb, ofl, 0, 0, 0);
        ofl = __builtin_amdgcn_mfma_f32_16x16x32_bf16(pf1, onesb, ofl, 0, 0, 0);
      }
    }

    #pragma unroll
    for (int r = 0; r < 4; ++r) {
      const int s = q0 + wave*16 + quad*4 + r;
      u16* orow = opart + obase + (size_t)s * 64;
      #pragma unroll
      for (int dht = 0; dht < 4; ++dht) orow[dht*16 + l16] = f2b(of[dht][r]);
      const float lr = __shfl(ofl[r], quad * 16);
      if (l16 == 0) { ml[mlbase + 2*s] = m[r]; ml[mlbase + 2*s + 1] = lr; }
    }
  }
}

// ---------- combine attention partials -> attnb bf16 [B,S,1024] ----------
__global__ __launch_bounds__(256) void attn_combine_kernel(
    const u16* __restrict__ opart, const float* __restrict__ ml,
    u16* __restrict__ out)
{
  const int t = threadIdx.x;
  const int s = blockIdx.x * 4 + (t >> 6);
  const int lane = t & 63;
  const int h = blockIdx.y, b = blockIdx.z;

  const size_t o0  = ((((size_t)0 * 2 + b) * 16 + h) * 2048 + s) * 64 + lane;
  const size_t o1  = ((((size_t)1 * 2 + b) * 16 + h) * 2048 + s) * 64 + lane;
  const size_t ml0 = ((((size_t)0 * 2 + b) * 16 + h) * 2048 + s) * 2;
  const size_t ml1 = ((((size_t)1 * 2 + b) * 16 + h) * 2048 + s) * 2;

  const float m0 = ml[ml0], l0 = ml[ml0 + 1];
  const float m1 = ml[ml1], l1 = ml[ml1 + 1];
  const float M  = fmaxf(m0, m1);
  const float w0 = __builtin_amdgcn_exp2f(m0 - M);
  const float w1 = __builtin_amdgcn_exp2f(m1 - M);
  const float L  = w0 * l0 + w1 * l1;
  const float o  = w0 * b2f(opart[o0]) + w1 * b2f(opart[o1]);
  out[((size_t)b * 2048 + s) * 1024 + h * 64 + lane] = f2b(o / L);
}

// ---------- K-split combine: out(fp32) = res + p0 + p1 + bias ----------
__global__ __launch_bounds__(256) void ksplit_combine_kernel(
    const u16* __restrict__ p0, const u16* __restrict__ p1,
    const float* __restrict__ res, const float* __restrict__ bias,
    float* __restrict__ out)
{
  const size_t i0 = ((size_t)blockIdx.x * 256 + threadIdx.x) * 8;
  usx8 a = *(const usx8*)(p0 + i0);
  usx8 c = *(const usx8*)(p1 + i0);
  const int col = (int)(i0 & 1023);
  floatx4 bv0 = *(const floatx4*)(bias + col);
  floatx4 bv1 = *(const floatx4*)(bias + col + 4);
  floatx4 h0 = *(const floatx4*)(res + i0);
  floatx4 h1 = *(const floatx4*)(res + i0 + 4);
  floatx4 o0, o1;
  #pragma unroll
  for (int i = 0; i < 4; ++i) o0[i] = h0[i] + b2f(a[i])   + b2f(c[i])   + bv0[i];
  #pragma unroll
  for (int i = 0; i < 4; ++i) o1[i] = h1[i] + b2f(a[4+i]) + b2f(c[4+i]) + bv1[i];
  *(floatx4*)(out + i0)     = o0;
  *(floatx4*)(out + i0 + 4) = o1;
}

// ---------- launch ----------
extern "C" void kernel_launch(void* const* d_in, const int* in_sizes, int n_in,
                              void* d_out, int out_size, void* d_ws, size_t ws_size,
                              hipStream_t stream) {
  const float* hidden    = (const float*)d_in[0];
  const float* w_attn    = (const float*)d_in[1];
  const float* b_attn    = (const float*)d_in[2];
  const float* w_proj    = (const float*)d_in[3];
  const float* b_proj    = (const float*)d_in[4];
  const float* w_fc      = (const float*)d_in[5];
  const float* b_fc      = (const float*)d_in[6];
  const float* w_fc_proj = (const float*)d_in[7];
  const float* b_fc_proj = (const float*)d_in[8];
  const float* ln1_w     = (const float*)d_in[9];
  const float* ln1_b     = (const float*)d_in[10];
  const float* ln2_w     = (const float*)d_in[11];
  const float* ln2_b     = (const float*)d_in[12];

  // Workspace layout (MB offsets), liveness-checked (round-6 notes)
  char* wsb = (char*)d_ws;
  u16*   qkvb  = (u16*)  (wsb + (size_t)( 0u << 20));  // 24 MB [4096,3072]
  u16*   xb    = (u16*)  (wsb + (size_t)(24u << 20));  //  8 MB [4096,1024]
  u16*   opart = (u16*)  (wsb + (size_t)(24u << 20));  // 16 MB (xb dead)
  float* mlbuf = (float*)(wsb + (size_t)(40u << 20));  //  2 MB
  u16*   attnb = (u16*)  (wsb + (size_t)(42u << 20));  //  8 MB [4096,1024]
  u16*   wqT   = (u16*)  (wsb + (size_t)(50u << 20));  //  6 MB [3072,1024]
  u16*   wpT   = (u16*)  (wsb + (size_t)(56u << 20));  //  2 MB [1024,1024]
  u16*   wfT   = (u16*)  (wsb + (size_t)(58u << 20));  //  8 MB [4096,1024]
  u16*   wfpT  = (u16*)  (wsb + (size_t)(66u << 20));  //  8 MB [1024,4096]
  u16*   pproj = (u16*)  (wsb + (size_t)(24u << 20));  // 16 MB (opart dead)
  float* hbuf  = (float*)(wsb + (size_t)(42u << 20));  // 16 MB fp32
  u16*   yb    = (u16*)  (wsb + (size_t)( 0u << 20));  //  8 MB (qkvb dead)
  u16*   fcb   = (u16*)  (wsb + (size_t)( 8u << 20));  // 32 MB
  u16*   pfcp0 = (u16*)  (wsb + (size_t)( 0u << 20));  //  8 MB (yb dead)
  u16*   pfcp1 = (u16*)  (wsb + (size_t)(58u << 20));  //  8 MB (wfT dead)
  const size_t zstr_fcp = ((size_t)58u << 20) / 2;

  // 0) weight transpose+convert (single launch)
  wtrans4_kernel<<<dim3(12288), 256, 0, stream>>>(
      w_attn, w_proj, w_fc, w_fc_proj, wqT, wpT, wfT, wfpT);

  // 1) x = LN1(hidden) -> bf16
  ln_bf16_kernel<<<4096, 256, 0, stream>>>(hidden, ln1_w, ln1_b, xb);
  // 2) qkv = x @ w_attn + b_attn -> bf16; q pre-scaled (flag 8)
  //    grid (24,32,1); XCD regions 12x x 8y
  gemm_mfma_kernel<128,128,12,4, 24,32,1, 2,4,1><<<dim3(24, 32, 1), 256, 0, stream>>>(
      xb, wqT, b_attn, nullptr, qkvb, 4096, 3072, 1024, 1024, 0);
  // 3) flash attention partials + combine
  attn_mfma_kernel<<<dim3(32, 16, 2), 256, 0, stream>>>(qkvb, opart, mlbuf);
  attn_combine_kernel<<<dim3(512, 16, 2), 256, 0, stream>>>(opart, mlbuf, attnb);
  // 4) proj partials: K-split x2; grid (16,32,2); regions 16x x 8y x 1z
  gemm_mfma_kernel<128,64,4,4, 16,32,2, 1,4,2><<<dim3(16, 32, 2), 256, 0, stream>>>(
      attnb, wpT, nullptr, nullptr, pproj, 4096, 1024, 1024, 512, 4194304);
  // 4b+5) h = hidden + p0 + p1 + b_proj; y = LN2(h)  (fused)
  combine_ln_kernel<<<4096, 256, 0, stream>>>(
      pproj, pproj + 4194304, hidden, b_proj, ln2_w, ln2_b, hbuf, yb);
  // 6) fc = gelu(y @ w_fc + b_fc); grid (32,32,1); regions 16x x 8y
  gemm_mfma_kernel<128,128,5,4, 32,32,1, 2,4,1><<<dim3(32, 32, 1), 256, 0, stream>>>(
      yb, wfT, b_fc, nullptr, fcb, 4096, 4096, 1024, 1024, 0);
  // 7) fc_proj partials: K-split x2; grid (16,32,2); regions 16x x 8y x 1z
  gemm_mfma_kernel<128,64,4,4, 16,32,2, 1,4,2><<<dim3(16, 32, 2), 256, 0, stream>>>(
      fcb, wfpT, nullptr, nullptr, pfcp0, 4096, 1024, 4096, 2048, zstr_fcp);
  // 8) out = h + p0 + p1 + b_fc_proj -> fp32
  ksplit_combine_kernel<<<dim3(2048), 256, 0, stream>>>(
      pfcp0, pfcp1, hbuf, b_fc_proj, (float*)d_out);
}